// Round 3
// baseline (287.974 us; speedup 1.0000x reference)
//
#include <hip/hip_runtime.h>
#include <stdint.h>

#define N_ROWS 8192
#define H_DIM  1024
#define I_DIM  4096

typedef unsigned short u16;
typedef __bf16 bf16x8 __attribute__((ext_vector_type(8)));
typedef float f32x4 __attribute__((ext_vector_type(4)));
typedef u16 u16x4 __attribute__((ext_vector_type(4)));

#define BAR()   asm volatile("s_barrier" ::: "memory")
#define LGKM0() do { asm volatile("s_waitcnt lgkmcnt(0)" ::: "memory"); __builtin_amdgcn_sched_barrier(0); } while (0)
#define VMW4()  do { asm volatile("s_waitcnt vmcnt(4)" ::: "memory"); __builtin_amdgcn_sched_barrier(0); } while (0)
#define VMW6()  do { asm volatile("s_waitcnt vmcnt(6)" ::: "memory"); __builtin_amdgcn_sched_barrier(0); } while (0)
#define VMW0()  do { asm volatile("s_waitcnt vmcnt(0)" ::: "memory"); __builtin_amdgcn_sched_barrier(0); } while (0)

__device__ __forceinline__ u16 f2bf(float f) {
    union { float f; uint32_t u; } v; v.f = f;
    uint32_t u = v.u;
    u += 0x7FFFu + ((u >> 16) & 1u);   // RNE
    return (u16)(u >> 16);
}

__device__ __forceinline__ float bf2f(u16 h) {
    union { uint32_t u; float f; } v; v.u = ((uint32_t)h) << 16;
    return v.f;
}

__device__ __forceinline__ float gelu_tanh(float x) {
    float u = 0.7978845608028654f * (x + 0.044715f * x * x * x);
    u = fminf(fmaxf(u, -15.f), 15.f);
    float e = __expf(2.f * u);
    float t = (e - 1.f) / (e + 1.f);
    return 0.5f * x * (1.f + t);
}

// ---- global -> LDS direct (16B per lane) ----
__device__ __forceinline__ void load_lds16(const void* g, void* l) {
    auto gp = reinterpret_cast<const __attribute__((address_space(1))) uint32_t*>(
        reinterpret_cast<uintptr_t>(g));
    auto lp = reinterpret_cast<__attribute__((address_space(3))) uint32_t*>(
        static_cast<uint32_t>(reinterpret_cast<uintptr_t>(l)));
    __builtin_amdgcn_global_load_lds(gp, lp, 16, 0, 0);
}

// =====================================================================
// GEMM1: hid = gelu(xln·W1g^T + bg) * (xln·W1l^T + bl)   (bf16 out)
// tile: 256 rows x 128 hid-cols; 512 thr / 8 waves (2M x 4N);
// wave: 128 rows x 32 cols x {gate,lin}. BK=32, 3-slot LDS ring (96 KiB).
// LDS slot: A[256][32] @0, B[256][32] @8192 (B rows 0-127=gate,128-255=lin)
// swizzle: LDS granule s holds global k-granule s ^ ((row>>1)&3).
// =====================================================================
__global__ __launch_bounds__(512, 2) void gemm1_gated(
    const u16* __restrict__ A, const u16* __restrict__ W,
    const float* __restrict__ bias, u16* __restrict__ hid)
{
    __shared__ u16 lds[3 * 16384];     // 96 KiB
    const int t = threadIdx.x;
    const int lane = t & 63, wid = t >> 6;
    const int wm = wid >> 2, wn = wid & 3;
    const int g = lane >> 4, r16 = lane & 15;

    int bid = blockIdx.x;
    bid = (bid & 7) * 128 + (bid >> 3);          // XCD swizzle (1024 % 8 == 0)
    const int brow = (bid >> 5) * 256;
    const int bcol = (bid & 31) * 128;

    // staging constants (per-thread)
    const int tr = t >> 2, ts = t & 3;
    const int tswz = ts ^ ((tr >> 1) & 3);
    const u16* pA  = A + (size_t)(brow + tr) * H_DIM + tswz * 8;
    const u16* pBg = W + (size_t)(bcol + tr) * H_DIM + tswz * 8;
    const u16* pBl = W + (size_t)(I_DIM + bcol + tr) * H_DIM + tswz * 8;
    const int dst = t * 8;

    // read constants (u16 offsets within slot)
    const int sRd   = (g ^ ((r16 >> 1) & 3)) * 8;
    const int offA  = (wm * 128 + r16) * 32 + sRd;   // + m*512
    const int offBg = (wn * 32 + r16) * 32 + sRd;    // + n*512
    const int offBl = offBg + 4096;                  // lin = B rows 128..255

    f32x4 accg[8][2] = {};
    f32x4 accl[8][2] = {};

    // prologue: stage K-tiles 0,1 into slots 0,1
#pragma unroll
    for (int p = 0; p < 2; ++p) {
        u16* dA = lds + p * 16384; u16* dB = dA + 8192;
        load_lds16(pA + p * 32,                 dA + dst);
        load_lds16(pA + 128 * H_DIM + p * 32,   dA + 4096 + dst);
        load_lds16(pBg + p * 32,                dB + dst);
        load_lds16(pBl + p * 32,                dB + 4096 + dst);
    }
    VMW4(); BAR();

    int slot = 0, s2 = 2;
    for (int kt = 0; kt < 32; ++kt) {
        const u16* lA = lds + slot * 16384;
        const u16* lB = lA + 8192;
        u16* dA = lds + s2 * 16384;
        u16* dB = dA + 8192;
        const bool st = (kt + 2 < 32);
        const int k2 = (kt + 2) * 32;
        bf16x8 af[4], bg[2], bl[2];

        // ---- S1: read A m0-3 + B gate; stage A half 0 ----
        if (st) load_lds16(pA + k2, dA + dst);
#pragma unroll
        for (int m = 0; m < 4; ++m) af[m] = *(const bf16x8*)(lA + offA + m * 512);
#pragma unroll
        for (int n = 0; n < 2; ++n) bg[n] = *(const bf16x8*)(lB + offBg + n * 512);
        BAR(); LGKM0(); __builtin_amdgcn_s_setprio(1);
#pragma unroll
        for (int m = 0; m < 4; ++m)
#pragma unroll
            for (int n = 0; n < 2; ++n)
                accg[m][n] = __builtin_amdgcn_mfma_f32_16x16x32_bf16(af[m], bg[n], accg[m][n], 0, 0, 0);
        __builtin_amdgcn_s_setprio(0); BAR();

        // ---- S2: read B lin; stage A half 1 ----
        if (st) load_lds16(pA + 128 * H_DIM + k2, dA + 4096 + dst);
#pragma unroll
        for (int n = 0; n < 2; ++n) bl[n] = *(const bf16x8*)(lB + offBl + n * 512);
        BAR(); LGKM0(); __builtin_amdgcn_s_setprio(1);
#pragma unroll
        for (int m = 0; m < 4; ++m)
#pragma unroll
            for (int n = 0; n < 2; ++n)
                accl[m][n] = __builtin_amdgcn_mfma_f32_16x16x32_bf16(af[m], bl[n], accl[m][n], 0, 0, 0);
        __builtin_amdgcn_s_setprio(0); BAR();

        // ---- S3: read A m4-7; stage B gate half ----
        if (st) load_lds16(pBg + k2, dB + dst);
#pragma unroll
        for (int m = 0; m < 4; ++m) af[m] = *(const bf16x8*)(lA + offA + (m + 4) * 512);
        BAR(); LGKM0(); __builtin_amdgcn_s_setprio(1);
#pragma unroll
        for (int m = 0; m < 4; ++m)
#pragma unroll
            for (int n = 0; n < 2; ++n)
                accl[m + 4][n] = __builtin_amdgcn_mfma_f32_16x16x32_bf16(af[m], bl[n], accl[m + 4][n], 0, 0, 0);
        __builtin_amdgcn_s_setprio(0); BAR();

        // ---- S4: stage B lin half; compute gate m4-7 ----
        if (st) load_lds16(pBl + k2, dB + 4096 + dst);
        BAR(); __builtin_amdgcn_s_setprio(1);
#pragma unroll
        for (int m = 0; m < 4; ++m)
#pragma unroll
            for (int n = 0; n < 2; ++n)
                accg[m + 4][n] = __builtin_amdgcn_mfma_f32_16x16x32_bf16(af[m], bg[n], accg[m + 4][n], 0, 0, 0);
        __builtin_amdgcn_s_setprio(0);
        if (st) { VMW4(); } else { VMW0(); }
        BAR();
        slot = (slot == 2) ? 0 : slot + 1;
        s2   = (s2 == 2) ? 0 : s2 + 1;
    }

    // epilogue: bias + gated gelu, bf16 store
#pragma unroll
    for (int n = 0; n < 2; ++n) {
        const int cg = bcol + wn * 32 + n * 16 + r16;
        const float bgv = bias[cg], blv = bias[I_DIM + cg];
#pragma unroll
        for (int m = 0; m < 8; ++m) {
            const int row = brow + wm * 128 + m * 16 + g * 4;
            u16* hp = hid + (size_t)row * I_DIM + cg;
#pragma unroll
            for (int r = 0; r < 4; ++r) {
                float gate = accg[m][n][r] + bgv;
                float lin  = accl[m][n][r] + blv;
                hp[(size_t)r * I_DIM] = f2bf(gelu_tanh(gate) * lin);
            }
        }
    }
}

// =====================================================================
// GEMM2: opb = hid·W2^T + b2  (bf16 out)
// tile: 256 rows x 128 cols; 256 thr / 4 waves (2M x 2N); wave 128x64.
// BK=32, NT=128, 3-slot ring (72 KiB -> 2 blocks/CU).
// LDS slot: A[256][32] @0, B[128][32] @8192.
// =====================================================================
__global__ __launch_bounds__(256, 2) void gemm2_k(
    const u16* __restrict__ A, const u16* __restrict__ W,
    const float* __restrict__ bias, u16* __restrict__ opb)
{
    __shared__ u16 lds[3 * 12288];     // 72 KiB
    const int t = threadIdx.x;
    const int lane = t & 63, wid = t >> 6;
    const int wm = wid >> 1, wn = wid & 1;
    const int g = lane >> 4, r16 = lane & 15;

    int bid = blockIdx.x;
    bid = (bid & 7) * 32 + (bid >> 3);           // XCD swizzle (256 % 8 == 0)
    const int brow = (bid >> 3) * 256;
    const int bcol = (bid & 7) * 128;

    const int tr = t >> 2, ts = t & 3;
    const int tswz = ts ^ ((tr >> 1) & 3);
    const u16* pA = A + (size_t)(brow + tr) * I_DIM + tswz * 8;   // + i*64*I_DIM
    const u16* pB = W + (size_t)(bcol + tr) * I_DIM + tswz * 8;   // + i*64*I_DIM
    const int dst = t * 8;

    const int sRd  = (g ^ ((r16 >> 1) & 3)) * 8;
    const int offA = (wm * 128 + r16) * 32 + sRd;        // + m*512
    const int offB = 8192 + (wn * 64 + r16) * 32 + sRd;  // + n*512

    f32x4 acc[8][4] = {};

    // prologue: stage K-tiles 0,1 (6 loads each)
#pragma unroll
    for (int p = 0; p < 2; ++p) {
        u16* dA = lds + p * 12288; u16* dB = dA + 8192;
#pragma unroll
        for (int i = 0; i < 4; ++i)
            load_lds16(pA + (size_t)i * 64 * I_DIM + p * 32, dA + i * 2048 + dst);
#pragma unroll
        for (int i = 0; i < 2; ++i)
            load_lds16(pB + (size_t)i * 64 * I_DIM + p * 32, dB + i * 2048 + dst);
    }
    VMW6(); BAR();

    int slot = 0, s2 = 2;
    for (int kt = 0; kt < 128; ++kt) {
        const u16* lA = lds + slot * 12288;
        u16* dA = lds + s2 * 12288;
        u16* dB = dA + 8192;
        const bool st = (kt + 2 < 128);
        const int k2 = (kt + 2) * 32;
        bf16x8 af[4], bf[4];

        // ---- S1: read A m0-3 + B n0-1; stage A i0,i1 ----
        if (st) {
            load_lds16(pA + k2, dA + dst);
            load_lds16(pA + (size_t)64 * I_DIM + k2, dA + 2048 + dst);
        }
#pragma unroll
        for (int m = 0; m < 4; ++m) af[m] = *(const bf16x8*)(lA + offA + m * 512);
#pragma unroll
        for (int n = 0; n < 2; ++n) bf[n] = *(const bf16x8*)(lA + offB + n * 512);
        BAR(); LGKM0(); __builtin_amdgcn_s_setprio(1);
#pragma unroll
        for (int m = 0; m < 4; ++m)
#pragma unroll
            for (int n = 0; n < 2; ++n)
                acc[m][n] = __builtin_amdgcn_mfma_f32_16x16x32_bf16(af[m], bf[n], acc[m][n], 0, 0, 0);
        __builtin_amdgcn_s_setprio(0); BAR();

        // ---- S2: read B n2-3; stage A i2,i3 ----
        if (st) {
            load_lds16(pA + (size_t)128 * I_DIM + k2, dA + 4096 + dst);
            load_lds16(pA + (size_t)192 * I_DIM + k2, dA + 6144 + dst);
        }
#pragma unroll
        for (int n = 2; n < 4; ++n) bf[n] = *(const bf16x8*)(lA + offB + n * 512);
        BAR(); LGKM0(); __builtin_amdgcn_s_setprio(1);
#pragma unroll
        for (int m = 0; m < 4; ++m)
#pragma unroll
            for (int n = 2; n < 4; ++n)
                acc[m][n] = __builtin_amdgcn_mfma_f32_16x16x32_bf16(af[m], bf[n], acc[m][n], 0, 0, 0);
        __builtin_amdgcn_s_setprio(0); BAR();

        // ---- S3: read A m4-7; stage B i0 ----
        if (st) load_lds16(pB + k2, dB + dst);
#pragma unroll
        for (int m = 0; m < 4; ++m) af[m] = *(const bf16x8*)(lA + offA + (m + 4) * 512);
        BAR(); LGKM0(); __builtin_amdgcn_s_setprio(1);
#pragma unroll
        for (int m = 0; m < 4; ++m)
#pragma unroll
            for (int n = 2; n < 4; ++n)
                acc[m + 4][n] = __builtin_amdgcn_mfma_f32_16x16x32_bf16(af[m], bf[n], acc[m + 4][n], 0, 0, 0);
        __builtin_amdgcn_s_setprio(0); BAR();

        // ---- S4: stage B i1; compute m4-7 x n0-1 ----
        if (st) load_lds16(pB + (size_t)64 * I_DIM + k2, dB + 2048 + dst);
        BAR(); __builtin_amdgcn_s_setprio(1);
#pragma unroll
        for (int m = 0; m < 4; ++m)
#pragma unroll
            for (int n = 0; n < 2; ++n)
                acc[m + 4][n] = __builtin_amdgcn_mfma_f32_16x16x32_bf16(af[m], bf[n], acc[m + 4][n], 0, 0, 0);
        __builtin_amdgcn_s_setprio(0);
        if (st) { VMW6(); } else { VMW0(); }
        BAR();
        slot = (slot == 2) ? 0 : slot + 1;
        s2   = (s2 == 2) ? 0 : s2 + 1;
    }

#pragma unroll
    for (int n = 0; n < 4; ++n) {
        const int cg = bcol + wn * 64 + n * 16 + r16;
        const float bv = bias[cg];
#pragma unroll
        for (int m = 0; m < 8; ++m) {
            const int row = brow + wm * 128 + m * 16 + g * 4;
            u16* op = opb + (size_t)row * H_DIM + cg;
#pragma unroll
            for (int r = 0; r < 4; ++r)
                op[(size_t)r * H_DIM] = f2bf(acc[m][n][r] + bv);
        }
    }
}

// ---- block mean/var over one row of 1024 (256 threads x 4 elems) ----
__device__ __forceinline__ void block_mean_var(float s, float s2, float* red, int t,
                                               float& mu, float& var) {
#pragma unroll
    for (int off = 32; off > 0; off >>= 1) {
        s  += __shfl_down(s, off);
        s2 += __shfl_down(s2, off);
    }
    const int wid = t >> 6;
    if ((t & 63) == 0) { red[wid] = s; red[4 + wid] = s2; }
    __syncthreads();
    if (t == 0) {
        float a = red[0] + red[1] + red[2] + red[3];
        float b = red[4] + red[5] + red[6] + red[7];
        red[0] = a * (1.f / H_DIM);
        red[1] = b * (1.f / H_DIM);
    }
    __syncthreads();
    mu = red[0];
    var = red[1] - mu * mu;
}

__global__ void ln_pre(const float* __restrict__ x, const float* __restrict__ w,
                       const float* __restrict__ b, u16* __restrict__ xln)
{
    __shared__ float red[8];
    const int row = blockIdx.x, t = threadIdx.x;
    const float4 v = reinterpret_cast<const float4*>(x + (size_t)row * H_DIM)[t];
    float mu, var;
    block_mean_var(v.x + v.y + v.z + v.w,
                   v.x * v.x + v.y * v.y + v.z * v.z + v.w * v.w, red, t, mu, var);
    const float rstd = rsqrtf(var + 1e-5f);
    const float4 wv = reinterpret_cast<const float4*>(w)[t];
    const float4 bv = reinterpret_cast<const float4*>(b)[t];
    u16x4 o;
    o.x = f2bf((v.x - mu) * rstd * wv.x + bv.x);
    o.y = f2bf((v.y - mu) * rstd * wv.y + bv.y);
    o.z = f2bf((v.z - mu) * rstd * wv.z + bv.z);
    o.w = f2bf((v.w - mu) * rstd * wv.w + bv.w);
    reinterpret_cast<u16x4*>(xln + (size_t)row * H_DIM)[t] = o;
}

__global__ void ln_post_res(const u16* __restrict__ op, const float* __restrict__ w,
                            const float* __restrict__ b, const float* __restrict__ x,
                            float* __restrict__ out)
{
    __shared__ float red[8];
    const int row = blockIdx.x, t = threadIdx.x;
    const u16x4 hv = reinterpret_cast<const u16x4*>(op + (size_t)row * H_DIM)[t];
    float4 v;
    v.x = bf2f(hv.x); v.y = bf2f(hv.y); v.z = bf2f(hv.z); v.w = bf2f(hv.w);
    float mu, var;
    block_mean_var(v.x + v.y + v.z + v.w,
                   v.x * v.x + v.y * v.y + v.z * v.z + v.w * v.w, red, t, mu, var);
    const float rstd = rsqrtf(var + 1e-5f);
    const float4 wv = reinterpret_cast<const float4*>(w)[t];
    const float4 bv = reinterpret_cast<const float4*>(b)[t];
    const float4 xv = reinterpret_cast<const float4*>(x + (size_t)row * H_DIM)[t];
    float4 o;
    o.x = (v.x - mu) * rstd * wv.x + bv.x + xv.x;
    o.y = (v.y - mu) * rstd * wv.y + bv.y + xv.y;
    o.z = (v.z - mu) * rstd * wv.z + bv.z + xv.z;
    o.w = (v.w - mu) * rstd * wv.w + bv.w + xv.w;
    reinterpret_cast<float4*>(out + (size_t)row * H_DIM)[t] = o;
}

__global__ void cvt_bf16(const float* __restrict__ in, u16* __restrict__ out, int n4) {
    int i = blockIdx.x * blockDim.x + threadIdx.x;
    if (i >= n4) return;
    float4 v = reinterpret_cast<const float4*>(in)[i];
    u16x4 o = { f2bf(v.x), f2bf(v.y), f2bf(v.z), f2bf(v.w) };
    reinterpret_cast<u16x4*>(out)[i] = o;
}

extern "C" void kernel_launch(void* const* d_in, const int* in_sizes, int n_in,
                              void* d_out, int out_size, void* d_ws, size_t ws_size,
                              hipStream_t stream)
{
    const float* x   = (const float*)d_in[0];
    const float* lnw = (const float*)d_in[1];
    const float* lnb = (const float*)d_in[2];
    const float* w1  = (const float*)d_in[3];
    const float* b1  = (const float*)d_in[4];
    const float* w2  = (const float*)d_in[5];
    const float* b2  = (const float*)d_in[6];
    const float* pw  = (const float*)d_in[7];
    const float* pb  = (const float*)d_in[8];
    float* out = (float*)d_out;

    // Workspace layout (peak 96 MiB), liveness-based aliasing:
    //   [0,16M)   xln   (live: ln_pre -> gemm1)
    //   [16,32M)  w1b   (live: cvt -> gemm1)
    //   [32,96M)  hid   (live: gemm1 -> gemm2)
    //   [0,8M)    w2b   (converted AFTER gemm1, over dead xln)
    //   [8,24M)   opb   (bf16, gemm2 out, over dead xln tail + w1b head)
    char* ws = (char*)d_ws;
    u16* xln = (u16*)(ws);
    u16* w1b = (u16*)(ws + (16u << 20));
    u16* hid = (u16*)(ws + (32u << 20));
    u16* w2b = (u16*)(ws);
    u16* opb = (u16*)(ws + (8u << 20));

    cvt_bf16<<<(2 * I_DIM * H_DIM / 4 + 255) / 256, 256, 0, stream>>>(w1, w1b, 2 * I_DIM * H_DIM / 4);
    ln_pre<<<N_ROWS, 256, 0, stream>>>(x, lnw, lnb, xln);
    gemm1_gated<<<1024, 512, 0, stream>>>(xln, w1b, b1, hid);
    cvt_bf16<<<(H_DIM * I_DIM / 4 + 255) / 256, 256, 0, stream>>>(w2, w2b, H_DIM * I_DIM / 4);
    gemm2_k<<<256, 256, 0, stream>>>(hid, w2b, b2, opb);
    ln_post_res<<<N_ROWS, 256, 0, stream>>>(opb, pw, pb, x, out);
}

// Round 4
// 276.863 us; speedup vs baseline: 1.0401x; 1.0401x over previous
//
#include <hip/hip_runtime.h>
#include <stdint.h>

#define N_ROWS 8192
#define H_DIM  1024
#define I_DIM  4096

typedef unsigned short u16;
typedef __bf16 bf16x8 __attribute__((ext_vector_type(8)));
typedef float f32x4 __attribute__((ext_vector_type(4)));
typedef u16 u16x4 __attribute__((ext_vector_type(4)));

#define BAR()   asm volatile("s_barrier" ::: "memory")
#define LGKM0() do { asm volatile("s_waitcnt lgkmcnt(0)" ::: "memory"); __builtin_amdgcn_sched_barrier(0); } while (0)
#define VMW(n)  do { asm volatile("s_waitcnt vmcnt(" #n ")" ::: "memory"); __builtin_amdgcn_sched_barrier(0); } while (0)

__device__ __forceinline__ u16 f2bf(float f) {
    union { float f; uint32_t u; } v; v.f = f;
    uint32_t u = v.u;
    u += 0x7FFFu + ((u >> 16) & 1u);   // RNE
    return (u16)(u >> 16);
}

__device__ __forceinline__ float bf2f(u16 h) {
    union { uint32_t u; float f; } v; v.u = ((uint32_t)h) << 16;
    return v.f;
}

__device__ __forceinline__ float gelu_tanh(float x) {
    float u = 0.7978845608028654f * (x + 0.044715f * x * x * x);
    u = fminf(fmaxf(u, -15.f), 15.f);
    float e = __expf(2.f * u);
    float t = (e - 1.f) / (e + 1.f);
    return 0.5f * x * (1.f + t);
}

// ---- global -> LDS direct (16B per lane) ----
__device__ __forceinline__ void load_lds16(const void* g, void* l) {
    auto gp = reinterpret_cast<const __attribute__((address_space(1))) uint32_t*>(
        reinterpret_cast<uintptr_t>(g));
    auto lp = reinterpret_cast<__attribute__((address_space(3))) uint32_t*>(
        static_cast<uint32_t>(reinterpret_cast<uintptr_t>(l)));
    __builtin_amdgcn_global_load_lds(gp, lp, 16, 0, 0);
}

// =====================================================================
// GEMM1: hid = gelu(xln·W1g^T + bg) * (xln·W1l^T + bl)   (bf16 out)
// tile 256 rows x 128 hid-cols; 512 thr / 8 waves (2M x 4N);
// wave: 128 rows x 32 cols x {gate,lin}. BK=64 k-split in 2 ks-halves.
// LDS slot (64 KiB): A[2ks][256][32] @0, B[2ks][256][32] @16384
//   (B rows 0-127 = gate cols, 128-255 = lin cols). 2 slots = 128 KiB.
// swizzle: granule slot = g ^ ((row>>1)&3)  (measured conflict-free, r3).
// Schedule: 2 phases/iter x 32 MFMA; P1 stages next-ks0 group (4 loads),
// P2 stages next-ks1 group; every phase ends vmcnt(4) (tail: vmcnt(0)).
// =====================================================================
__global__ __launch_bounds__(512, 2) void gemm1_gated(
    const u16* __restrict__ A, const u16* __restrict__ W,
    const float* __restrict__ bias, u16* __restrict__ hid)
{
    __shared__ u16 lds[2 * 32768];     // 128 KiB
    const int t = threadIdx.x;
    const int lane = t & 63, wid = t >> 6;
    const int wm = wid >> 2, wn = wid & 3;
    const int g = lane >> 4, r16 = lane & 15;

    const int brow = blockIdx.y * 256;
    const int bcol = blockIdx.x * 128;

    // staging constants: thread t covers row (t>>2) of a 128-row chunk,
    // granule (t&3) of a 32-k half; fetch global granule (t&3)^((t>>3)&3).
    const int tr = t >> 2;
    const int swz8 = ((t & 3) ^ ((t >> 3) & 3)) * 8;
    const u16* pA  = A + (size_t)(brow + tr) * H_DIM + swz8;
    const u16* pBg = W + (size_t)(bcol + tr) * H_DIM + swz8;
    const u16* pBl = W + (size_t)(I_DIM + bcol + tr) * H_DIM + swz8;
    const int dst = t * 8;

    // read constants (u16 offsets within slot)
    const int sl    = (g ^ ((r16 >> 1) & 3)) * 8;
    const int rdA   = (wm * 128 + r16) * 32 + sl;            // + ks*8192 + m*512
    const int rdBg  = 16384 + (wn * 32 + r16) * 32 + sl;     // + ks*8192 + n*512
    const int rdBl  = rdBg + 4096;                           // lin rows +128

    f32x4 accg[8][2] = {};
    f32x4 accl[8][2] = {};

    // prologue: stage tile 0 into slot 0: [A(ks0,h0),A(ks0,h1),Bg(ks0),Bl(ks0),
    //                                      A(ks1,h0),A(ks1,h1),Bg(ks1),Bl(ks1)]
#pragma unroll
    for (int s = 0; s < 2; ++s) {
        load_lds16(pA + s * 32,                 lds + s * 8192 + dst);
        load_lds16(pA + 128 * H_DIM + s * 32,   lds + s * 8192 + 4096 + dst);
        load_lds16(pBg + s * 32,                lds + 16384 + s * 8192 + dst);
        load_lds16(pBl + s * 32,                lds + 16384 + s * 8192 + 4096 + dst);
    }
    VMW(4); BAR();

    const int NT = H_DIM / 64;   // 16
    for (int kt = 0; kt < NT; ++kt) {
        const u16* lA = lds + (kt & 1) * 32768;
        u16* dS = lds + ((kt & 1) ^ 1) * 32768;
        const bool st = (kt + 1 < NT);
        const int k1 = (kt + 1) * 64;
        const bool tail = (kt == NT - 1);

#pragma unroll
        for (int ks = 0; ks < 2; ++ks) {
            bf16x8 af[8], bg[2], bl[2];
#pragma unroll
            for (int m = 0; m < 8; ++m) af[m] = *(const bf16x8*)(lA + ks * 8192 + rdA + m * 512);
#pragma unroll
            for (int n = 0; n < 2; ++n) {
                bg[n] = *(const bf16x8*)(lA + ks * 8192 + rdBg + n * 512);
                bl[n] = *(const bf16x8*)(lA + ks * 8192 + rdBl + n * 512);
            }
            if (st) {   // stage kt+1's ks-group into the other slot
                load_lds16(pA + k1 + ks * 32,               dS + ks * 8192 + dst);
                load_lds16(pA + 128 * H_DIM + k1 + ks * 32, dS + ks * 8192 + 4096 + dst);
                load_lds16(pBg + k1 + ks * 32,              dS + 16384 + ks * 8192 + dst);
                load_lds16(pBl + k1 + ks * 32,              dS + 16384 + ks * 8192 + 4096 + dst);
            }
            if (tail) { VMW(0); } else { VMW(4); }
            BAR(); LGKM0();
            __builtin_amdgcn_s_setprio(1);
#pragma unroll
            for (int m = 0; m < 8; ++m)
#pragma unroll
                for (int n = 0; n < 2; ++n) {
                    accg[m][n] = __builtin_amdgcn_mfma_f32_16x16x32_bf16(af[m], bg[n], accg[m][n], 0, 0, 0);
                    accl[m][n] = __builtin_amdgcn_mfma_f32_16x16x32_bf16(af[m], bl[n], accl[m][n], 0, 0, 0);
                }
            __builtin_amdgcn_s_setprio(0);
            BAR();
        }
    }

    // epilogue: bias + gated gelu, bf16 store
#pragma unroll
    for (int n = 0; n < 2; ++n) {
        const int cg = bcol + wn * 32 + n * 16 + r16;
        const float bgv = bias[cg], blv = bias[I_DIM + cg];
#pragma unroll
        for (int m = 0; m < 8; ++m) {
            const int row = brow + wm * 128 + m * 16 + g * 4;
            u16* hp = hid + (size_t)row * I_DIM + cg;
#pragma unroll
            for (int r = 0; r < 4; ++r) {
                float gate = accg[m][n][r] + bgv;
                float lin  = accl[m][n][r] + blv;
                hp[(size_t)r * I_DIM] = f2bf(gelu_tanh(gate) * lin);
            }
        }
    }
}

// =====================================================================
// GEMM2: opb = hid·W2^T + b2  (bf16 out)
// tile 256 rows x 128 cols; 512 thr / 8 waves (4M x 2N); wave 64x64.
// BK=64 k-split. LDS slot (48 KiB): A[2][256][32] @0, B[2][128][32] @16384.
// 2 phases/iter x 16 MFMA; per-phase stage group = 3 loads; vmcnt(3).
// =====================================================================
__global__ __launch_bounds__(512, 2) void gemm2_k(
    const u16* __restrict__ A, const u16* __restrict__ W,
    const float* __restrict__ bias, u16* __restrict__ opb)
{
    __shared__ u16 lds[2 * 24576];     // 96 KiB
    const int t = threadIdx.x;
    const int lane = t & 63, wid = t >> 6;
    const int wm = wid >> 1, wn = wid & 1;
    const int g = lane >> 4, r16 = lane & 15;

    const int brow = blockIdx.y * 256;
    const int bcol = blockIdx.x * 128;

    const int tr = t >> 2;
    const int swz8 = ((t & 3) ^ ((t >> 3) & 3)) * 8;
    const u16* pA = A + (size_t)(brow + tr) * I_DIM + swz8;
    const u16* pB = W + (size_t)(bcol + tr) * I_DIM + swz8;
    const int dst = t * 8;

    const int sl   = (g ^ ((r16 >> 1) & 3)) * 8;
    const int rdA  = (wm * 64 + r16) * 32 + sl;              // + ks*8192 + m*512
    const int rdB  = 16384 + (wn * 64 + r16) * 32 + sl;      // + ks*4096 + n*512

    f32x4 acc[4][4] = {};

    // prologue: [A(ks0,h0),A(ks0,h1),B(ks0), A(ks1,h0),A(ks1,h1),B(ks1)]
#pragma unroll
    for (int s = 0; s < 2; ++s) {
        load_lds16(pA + s * 32,               lds + s * 8192 + dst);
        load_lds16(pA + 128 * I_DIM + s * 32, lds + s * 8192 + 4096 + dst);
        load_lds16(pB + s * 32,               lds + 16384 + s * 4096 + dst);
    }
    VMW(3); BAR();

    const int NT = I_DIM / 64;   // 64
    for (int kt = 0; kt < NT; ++kt) {
        const u16* lA = lds + (kt & 1) * 24576;
        u16* dS = lds + ((kt & 1) ^ 1) * 24576;
        const bool st = (kt + 1 < NT);
        const int k1 = (kt + 1) * 64;
        const bool tail = (kt == NT - 1);

#pragma unroll
        for (int ks = 0; ks < 2; ++ks) {
            bf16x8 af[4], bf[4];
#pragma unroll
            for (int m = 0; m < 4; ++m) af[m] = *(const bf16x8*)(lA + ks * 8192 + rdA + m * 512);
#pragma unroll
            for (int n = 0; n < 4; ++n) bf[n] = *(const bf16x8*)(lA + ks * 4096 + rdB + n * 512);
            if (st) {
                load_lds16(pA + k1 + ks * 32,               dS + ks * 8192 + dst);
                load_lds16(pA + 128 * I_DIM + k1 + ks * 32, dS + ks * 8192 + 4096 + dst);
                load_lds16(pB + k1 + ks * 32,               dS + 16384 + ks * 4096 + dst);
            }
            if (tail) { VMW(0); } else { VMW(3); }
            BAR(); LGKM0();
            __builtin_amdgcn_s_setprio(1);
#pragma unroll
            for (int m = 0; m < 4; ++m)
#pragma unroll
                for (int n = 0; n < 4; ++n)
                    acc[m][n] = __builtin_amdgcn_mfma_f32_16x16x32_bf16(af[m], bf[n], acc[m][n], 0, 0, 0);
            __builtin_amdgcn_s_setprio(0);
            BAR();
        }
    }

#pragma unroll
    for (int n = 0; n < 4; ++n) {
        const int cg = bcol + wn * 64 + n * 16 + r16;
        const float bv = bias[cg];
#pragma unroll
        for (int m = 0; m < 4; ++m) {
            const int row = brow + wm * 64 + m * 16 + g * 4;
            u16* op = opb + (size_t)row * H_DIM + cg;
#pragma unroll
            for (int r = 0; r < 4; ++r)
                op[(size_t)r * H_DIM] = f2bf(acc[m][n][r] + bv);
        }
    }
}

// ---- block mean/var over one row of 1024 (256 threads x 4 elems) ----
__device__ __forceinline__ void block_mean_var(float s, float s2, float* red, int t,
                                               float& mu, float& var) {
#pragma unroll
    for (int off = 32; off > 0; off >>= 1) {
        s  += __shfl_down(s, off);
        s2 += __shfl_down(s2, off);
    }
    const int wid = t >> 6;
    if ((t & 63) == 0) { red[wid] = s; red[4 + wid] = s2; }
    __syncthreads();
    if (t == 0) {
        float a = red[0] + red[1] + red[2] + red[3];
        float b = red[4] + red[5] + red[6] + red[7];
        red[0] = a * (1.f / H_DIM);
        red[1] = b * (1.f / H_DIM);
    }
    __syncthreads();
    mu = red[0];
    var = red[1] - mu * mu;
}

__global__ void ln_pre(const float* __restrict__ x, const float* __restrict__ w,
                       const float* __restrict__ b, u16* __restrict__ xln)
{
    __shared__ float red[8];
    const int row = blockIdx.x, t = threadIdx.x;
    const float4 v = reinterpret_cast<const float4*>(x + (size_t)row * H_DIM)[t];
    float mu, var;
    block_mean_var(v.x + v.y + v.z + v.w,
                   v.x * v.x + v.y * v.y + v.z * v.z + v.w * v.w, red, t, mu, var);
    const float rstd = rsqrtf(var + 1e-5f);
    const float4 wv = reinterpret_cast<const float4*>(w)[t];
    const float4 bv = reinterpret_cast<const float4*>(b)[t];
    u16x4 o;
    o.x = f2bf((v.x - mu) * rstd * wv.x + bv.x);
    o.y = f2bf((v.y - mu) * rstd * wv.y + bv.y);
    o.z = f2bf((v.z - mu) * rstd * wv.z + bv.z);
    o.w = f2bf((v.w - mu) * rstd * wv.w + bv.w);
    reinterpret_cast<u16x4*>(xln + (size_t)row * H_DIM)[t] = o;
}

__global__ void ln_post_res(const u16* __restrict__ op, const float* __restrict__ w,
                            const float* __restrict__ b, const float* __restrict__ x,
                            float* __restrict__ out)
{
    __shared__ float red[8];
    const int row = blockIdx.x, t = threadIdx.x;
    const u16x4 hv = reinterpret_cast<const u16x4*>(op + (size_t)row * H_DIM)[t];
    float4 v;
    v.x = bf2f(hv.x); v.y = bf2f(hv.y); v.z = bf2f(hv.z); v.w = bf2f(hv.w);
    float mu, var;
    block_mean_var(v.x + v.y + v.z + v.w,
                   v.x * v.x + v.y * v.y + v.z * v.z + v.w * v.w, red, t, mu, var);
    const float rstd = rsqrtf(var + 1e-5f);
    const float4 wv = reinterpret_cast<const float4*>(w)[t];
    const float4 bv = reinterpret_cast<const float4*>(b)[t];
    const float4 xv = reinterpret_cast<const float4*>(x + (size_t)row * H_DIM)[t];
    float4 o;
    o.x = (v.x - mu) * rstd * wv.x + bv.x + xv.x;
    o.y = (v.y - mu) * rstd * wv.y + bv.y + xv.y;
    o.z = (v.z - mu) * rstd * wv.z + bv.z + xv.z;
    o.w = (v.w - mu) * rstd * wv.w + bv.w + xv.w;
    reinterpret_cast<float4*>(out + (size_t)row * H_DIM)[t] = o;
}

__global__ void cvt_bf16(const float* __restrict__ in, u16* __restrict__ out, int n4) {
    int i = blockIdx.x * blockDim.x + threadIdx.x;
    if (i >= n4) return;
    float4 v = reinterpret_cast<const float4*>(in)[i];
    u16x4 o = { f2bf(v.x), f2bf(v.y), f2bf(v.z), f2bf(v.w) };
    reinterpret_cast<u16x4*>(out)[i] = o;
}

extern "C" void kernel_launch(void* const* d_in, const int* in_sizes, int n_in,
                              void* d_out, int out_size, void* d_ws, size_t ws_size,
                              hipStream_t stream)
{
    const float* x   = (const float*)d_in[0];
    const float* lnw = (const float*)d_in[1];
    const float* lnb = (const float*)d_in[2];
    const float* w1  = (const float*)d_in[3];
    const float* b1  = (const float*)d_in[4];
    const float* w2  = (const float*)d_in[5];
    const float* b2  = (const float*)d_in[6];
    const float* pw  = (const float*)d_in[7];
    const float* pb  = (const float*)d_in[8];
    float* out = (float*)d_out;

    // Workspace layout (peak 96 MiB), liveness-based aliasing:
    //   [0,16M)   xln   (live: ln_pre -> gemm1)
    //   [16,32M)  w1b   (live: cvt -> gemm1)
    //   [32,96M)  hid   (live: gemm1 -> gemm2)
    //   [0,8M)    w2b   (converted AFTER gemm1, over dead xln)
    //   [8,24M)   opb   (bf16, gemm2 out, over dead xln tail + w1b head)
    char* ws = (char*)d_ws;
    u16* xln = (u16*)(ws);
    u16* w1b = (u16*)(ws + (16u << 20));
    u16* hid = (u16*)(ws + (32u << 20));
    u16* w2b = (u16*)(ws);
    u16* opb = (u16*)(ws + (8u << 20));

    cvt_bf16<<<(2 * I_DIM * H_DIM / 4 + 255) / 256, 256, 0, stream>>>(w1, w1b, 2 * I_DIM * H_DIM / 4);
    ln_pre<<<N_ROWS, 256, 0, stream>>>(x, lnw, lnb, xln);
    gemm1_gated<<<dim3(I_DIM / 128, N_ROWS / 256), 512, 0, stream>>>(xln, w1b, b1, hid);
    cvt_bf16<<<(H_DIM * I_DIM / 4 + 255) / 256, 256, 0, stream>>>(w2, w2b, H_DIM * I_DIM / 4);
    gemm2_k<<<dim3(H_DIM / 128, N_ROWS / 256), 512, 0, stream>>>(hid, w2b, b2, opb);
    ln_post_res<<<N_ROWS, 256, 0, stream>>>(opb, pw, pb, x, out);
}

// Round 5
// 274.855 us; speedup vs baseline: 1.0477x; 1.0073x over previous
//
#include <hip/hip_runtime.h>
#include <stdint.h>

#define N_ROWS 8192
#define H_DIM  1024
#define I_DIM  4096

typedef unsigned short u16;
typedef __bf16 bf16x8 __attribute__((ext_vector_type(8)));
typedef float f32x4 __attribute__((ext_vector_type(4)));
typedef u16 u16x4 __attribute__((ext_vector_type(4)));

#define BAR()   asm volatile("s_barrier" ::: "memory")
#define LGKM0() do { asm volatile("s_waitcnt lgkmcnt(0)" ::: "memory"); __builtin_amdgcn_sched_barrier(0); } while (0)
#define VMW(n)  do { asm volatile("s_waitcnt vmcnt(" #n ")" ::: "memory"); __builtin_amdgcn_sched_barrier(0); } while (0)

__device__ __forceinline__ u16 f2bf(float f) {
    union { float f; uint32_t u; } v; v.f = f;
    uint32_t u = v.u;
    u += 0x7FFFu + ((u >> 16) & 1u);   // RNE
    return (u16)(u >> 16);
}

__device__ __forceinline__ float bf2f(u16 h) {
    union { uint32_t u; float f; } v; v.u = ((uint32_t)h) << 16;
    return v.f;
}

__device__ __forceinline__ float gelu_tanh(float x) {
    float u = 0.7978845608028654f * (x + 0.044715f * x * x * x);
    u = fminf(fmaxf(u, -15.f), 15.f);
    float e = __expf(2.f * u);
    float t = (e - 1.f) / (e + 1.f);
    return 0.5f * x * (1.f + t);
}

// ---- global -> LDS direct (16B per lane) ----
__device__ __forceinline__ void load_lds16(const void* g, void* l) {
    auto gp = reinterpret_cast<const __attribute__((address_space(1))) uint32_t*>(
        reinterpret_cast<uintptr_t>(g));
    auto lp = reinterpret_cast<__attribute__((address_space(3))) uint32_t*>(
        static_cast<uint32_t>(reinterpret_cast<uintptr_t>(l)));
    __builtin_amdgcn_global_load_lds(gp, lp, 16, 0, 0);
}

// =====================================================================
// GEMM1: hid = gelu(xln·W1g^T + bg) * (xln·W1l^T + bl)   (bf16 out)
// tile 256 rows x 128 hid-cols (=256 W-rows, gate/lin interleaved so each
// wave owns 32 gate + the SAME 32 lin cols -> in-register gelu epilogue).
// 512 thr / 8 waves (2M x 4N); per-wave 128 rows x 64 B-cols.
// BK=32; ring-4 LDS (4 x 32 KiB: A[256][32] @0, B[256][32] @8192 u16).
// Pipeline: compute tile t while staging tile t+3 (2 tiles of cover);
// end-of-tile vmcnt(8) keeps 8 loads (t+2,t+3) in flight. 2 phases/tile,
// 16 MFMA each, setprio(1) around MFMA.
// swizzle: k-granule g' = g ^ ((row>>1)&3)  (measured 0-conflict, r4).
// =====================================================================
__global__ __launch_bounds__(512, 2) void gemm1_gated(
    const u16* __restrict__ A, const u16* __restrict__ W,
    const float* __restrict__ bias, u16* __restrict__ hid)
{
    __shared__ u16 lds[4 * 16384];     // 128 KiB
    const int t = threadIdx.x;
    const int lane = t & 63, wid = t >> 6;
    const int wm = wid >> 2, wn = wid & 3;
    const int g = lane >> 4, r16 = lane & 15;

    const int brow = blockIdx.y * 256;
    const int bcol = blockIdx.x * 128;

    // staging: thread t covers LDS rows (t>>2) and (t>>2)+128, granule t&3;
    // global k-granule = (t&3) ^ ((t>>3)&3)  (== granule ^ ((row>>1)&3)).
    const int tr = t >> 2;
    const int swz8 = ((t & 3) ^ ((t >> 3) & 3)) * 8;
    const u16* pA = A + (size_t)(brow + tr) * H_DIM + swz8;
    // B LDS row j: wave (j>>6) owns it; f=j&63: f<32 -> gate col, f>=32 -> lin col
    const int j0 = tr, j1 = tr + 128;
    const int cj0 = bcol + (j0 >> 6) * 32 + (j0 & 31);
    const int cj1 = bcol + (j1 >> 6) * 32 + (j1 & 31);
    const int gr0 = ((j0 & 63) < 32) ? cj0 : (I_DIM + cj0);
    const int gr1 = ((j1 & 63) < 32) ? cj1 : (I_DIM + cj1);
    const u16* pB0 = W + (size_t)gr0 * H_DIM + swz8;
    const u16* pB1 = W + (size_t)gr1 * H_DIM + swz8;
    const int dst = t * 8;

    // read offsets (u16 units within a buffer)
    const int sl  = (g ^ ((r16 >> 1) & 3)) * 8;
    const int rdA = (wm * 128 + r16) * 32 + sl;          // + m*512
    const int rdB = 8192 + (wn * 64 + r16) * 32 + sl;    // + n*512 gate; +1024 lin

    f32x4 accg[8][2] = {};
    f32x4 accl[8][2] = {};

    // prologue: stage tiles 0,1,2 into buffers 0,1,2 (12 loads)
#pragma unroll
    for (int p = 0; p < 3; ++p) {
        u16* S = lds + p * 16384;
        load_lds16(pA + p * 32,                        S + dst);
        load_lds16(pA + (size_t)128 * H_DIM + p * 32,  S + 4096 + dst);
        load_lds16(pB0 + p * 32,                       S + 8192 + dst);
        load_lds16(pB1 + p * 32,                       S + 12288 + dst);
    }
    VMW(8); BAR();   // tile 0 landed; tiles 1,2 in flight

    int bc = 0, bs = 3;
    const int NT = H_DIM / 32;   // 32
    for (int kt = 0; kt < NT; ++kt) {
        const u16* L = lds + bc * 16384;
        u16* S = lds + bs * 16384;
        const bool st = (kt + 3 < NT);
        const int kG = (kt + 3) * 32;
        bf16x8 af[8], bb[2];

        // ---- phase 0: stage A(t+3); read af[8] + gate B; 16 MFMA gate ----
        if (st) {
            load_lds16(pA + kG,                        S + dst);
            load_lds16(pA + (size_t)128 * H_DIM + kG,  S + 4096 + dst);
        }
#pragma unroll
        for (int m = 0; m < 8; ++m) af[m] = *(const bf16x8*)(L + rdA + m * 512);
#pragma unroll
        for (int n = 0; n < 2; ++n) bb[n] = *(const bf16x8*)(L + rdB + n * 512);
        BAR(); LGKM0();
        __builtin_amdgcn_s_setprio(1);
#pragma unroll
        for (int m = 0; m < 8; ++m)
#pragma unroll
            for (int n = 0; n < 2; ++n)
                accg[m][n] = __builtin_amdgcn_mfma_f32_16x16x32_bf16(af[m], bb[n], accg[m][n], 0, 0, 0);
        __builtin_amdgcn_s_setprio(0);
        BAR();

        // ---- phase 1: stage B(t+3); read lin B; 16 MFMA lin (af reused) ----
        if (st) {
            load_lds16(pB0 + kG, S + 8192 + dst);
            load_lds16(pB1 + kG, S + 12288 + dst);
        }
#pragma unroll
        for (int n = 0; n < 2; ++n) bb[n] = *(const bf16x8*)(L + rdB + 1024 + n * 512);
        BAR(); LGKM0();
        __builtin_amdgcn_s_setprio(1);
#pragma unroll
        for (int m = 0; m < 8; ++m)
#pragma unroll
            for (int n = 0; n < 2; ++n)
                accl[m][n] = __builtin_amdgcn_mfma_f32_16x16x32_bf16(af[m], bb[n], accl[m][n], 0, 0, 0);
        __builtin_amdgcn_s_setprio(0);
        // end-of-tile wait: need tile kt+1 landed; tiles kt+2,kt+3 stay in flight
        if (kt < NT - 3)      { VMW(8); }
        else if (kt == NT - 3){ VMW(4); }
        else                  { VMW(0); }
        BAR();
        bc = (bc + 1) & 3;
        bs = (bs + 1) & 3;
    }

    // epilogue: bias + gated gelu, bf16 store (gate/lin both in-register)
#pragma unroll
    for (int n = 0; n < 2; ++n) {
        const int cg = bcol + wn * 32 + n * 16 + r16;
        const float bgv = bias[cg], blv = bias[I_DIM + cg];
#pragma unroll
        for (int m = 0; m < 8; ++m) {
            const int row = brow + wm * 128 + m * 16 + g * 4;
            u16* hp = hid + (size_t)row * I_DIM + cg;
#pragma unroll
            for (int r = 0; r < 4; ++r) {
                float gate = accg[m][n][r] + bgv;
                float lin  = accl[m][n][r] + blv;
                hp[(size_t)r * I_DIM] = f2bf(gelu_tanh(gate) * lin);
            }
        }
    }
}

// =====================================================================
// GEMM2: opb = hid·W2^T + b2  (bf16 out)
// tile 256 rows x 128 cols; 512 thr / 8 waves (4M x 2N); per-wave 64x64.
// BK=32; ring-5 LDS (5 x 24 KiB: A[256][32] @0, B[128][32] @8192 u16).
// Pipeline: compute tile t while staging t+4 (3 tiles of cover);
// steady vmcnt(9); 1 phase/tile, 16 MFMA.
// =====================================================================
__global__ __launch_bounds__(512, 2) void gemm2_k(
    const u16* __restrict__ A, const u16* __restrict__ W,
    const float* __restrict__ bias, u16* __restrict__ opb)
{
    __shared__ u16 lds[5 * 12288];     // 120 KiB
    const int t = threadIdx.x;
    const int lane = t & 63, wid = t >> 6;
    const int wm = wid >> 1, wn = wid & 1;
    const int g = lane >> 4, r16 = lane & 15;

    const int brow = blockIdx.y * 256;
    const int bcol = blockIdx.x * 128;

    const int tr = t >> 2;
    const int swz8 = ((t & 3) ^ ((t >> 3) & 3)) * 8;
    const u16* pA = A + (size_t)(brow + tr) * I_DIM + swz8;
    const u16* pB = W + (size_t)(bcol + tr) * I_DIM + swz8;
    const int dst = t * 8;

    const int sl  = (g ^ ((r16 >> 1) & 3)) * 8;
    const int rdA = (wm * 64 + r16) * 32 + sl;           // + m*512
    const int rdB = 8192 + (wn * 64 + r16) * 32 + sl;    // + n*512

    f32x4 acc[4][4] = {};

    // prologue: stage tiles 0..3 into buffers 0..3 (12 loads)
#pragma unroll
    for (int p = 0; p < 4; ++p) {
        u16* S = lds + p * 12288;
        load_lds16(pA + p * 32,                        S + dst);
        load_lds16(pA + (size_t)128 * I_DIM + p * 32,  S + 4096 + dst);
        load_lds16(pB + p * 32,                        S + 8192 + dst);
    }
    VMW(9); BAR();   // tile 0 landed; 1,2,3 in flight

    int bc = 0, bs = 4;
    const int NT = I_DIM / 32;   // 128
    for (int kt = 0; kt < NT; ++kt) {
        const u16* L = lds + bc * 12288;
        u16* S = lds + bs * 12288;
        if (kt + 4 < NT) {
            const int kG = (kt + 4) * 32;
            load_lds16(pA + kG,                        S + dst);
            load_lds16(pA + (size_t)128 * I_DIM + kG,  S + 4096 + dst);
            load_lds16(pB + kG,                        S + 8192 + dst);
        }
        bf16x8 af[4], bf[4];
#pragma unroll
        for (int m = 0; m < 4; ++m) af[m] = *(const bf16x8*)(L + rdA + m * 512);
#pragma unroll
        for (int n = 0; n < 4; ++n) bf[n] = *(const bf16x8*)(L + rdB + n * 512);
        BAR(); LGKM0();
        __builtin_amdgcn_s_setprio(1);
#pragma unroll
        for (int m = 0; m < 4; ++m)
#pragma unroll
            for (int n = 0; n < 4; ++n)
                acc[m][n] = __builtin_amdgcn_mfma_f32_16x16x32_bf16(af[m], bf[n], acc[m][n], 0, 0, 0);
        __builtin_amdgcn_s_setprio(0);
        if (kt < NT - 4)      { VMW(9); }
        else if (kt == NT - 4){ VMW(6); }
        else if (kt == NT - 3){ VMW(3); }
        else                  { VMW(0); }
        BAR();
        bc = (bc == 4) ? 0 : bc + 1;
        bs = (bs == 4) ? 0 : bs + 1;
    }

#pragma unroll
    for (int n = 0; n < 4; ++n) {
        const int cg = bcol + wn * 64 + n * 16 + r16;
        const float bv = bias[cg];
#pragma unroll
        for (int m = 0; m < 4; ++m) {
            const int row = brow + wm * 64 + m * 16 + g * 4;
            u16* op = opb + (size_t)row * H_DIM + cg;
#pragma unroll
            for (int r = 0; r < 4; ++r)
                op[(size_t)r * H_DIM] = f2bf(acc[m][n][r] + bv);
        }
    }
}

// ---- block mean/var over one row of 1024 (256 threads x 4 elems) ----
__device__ __forceinline__ void block_mean_var(float s, float s2, float* red, int t,
                                               float& mu, float& var) {
#pragma unroll
    for (int off = 32; off > 0; off >>= 1) {
        s  += __shfl_down(s, off);
        s2 += __shfl_down(s2, off);
    }
    const int wid = t >> 6;
    if ((t & 63) == 0) { red[wid] = s; red[4 + wid] = s2; }
    __syncthreads();
    if (t == 0) {
        float a = red[0] + red[1] + red[2] + red[3];
        float b = red[4] + red[5] + red[6] + red[7];
        red[0] = a * (1.f / H_DIM);
        red[1] = b * (1.f / H_DIM);
    }
    __syncthreads();
    mu = red[0];
    var = red[1] - mu * mu;
}

__global__ void ln_pre(const float* __restrict__ x, const float* __restrict__ w,
                       const float* __restrict__ b, u16* __restrict__ xln)
{
    __shared__ float red[8];
    const int row = blockIdx.x, t = threadIdx.x;
    const float4 v = reinterpret_cast<const float4*>(x + (size_t)row * H_DIM)[t];
    float mu, var;
    block_mean_var(v.x + v.y + v.z + v.w,
                   v.x * v.x + v.y * v.y + v.z * v.z + v.w * v.w, red, t, mu, var);
    const float rstd = rsqrtf(var + 1e-5f);
    const float4 wv = reinterpret_cast<const float4*>(w)[t];
    const float4 bv = reinterpret_cast<const float4*>(b)[t];
    u16x4 o;
    o.x = f2bf((v.x - mu) * rstd * wv.x + bv.x);
    o.y = f2bf((v.y - mu) * rstd * wv.y + bv.y);
    o.z = f2bf((v.z - mu) * rstd * wv.z + bv.z);
    o.w = f2bf((v.w - mu) * rstd * wv.w + bv.w);
    reinterpret_cast<u16x4*>(xln + (size_t)row * H_DIM)[t] = o;
}

__global__ void ln_post_res(const u16* __restrict__ op, const float* __restrict__ w,
                            const float* __restrict__ b, const float* __restrict__ x,
                            float* __restrict__ out)
{
    __shared__ float red[8];
    const int row = blockIdx.x, t = threadIdx.x;
    const u16x4 hv = reinterpret_cast<const u16x4*>(op + (size_t)row * H_DIM)[t];
    float4 v;
    v.x = bf2f(hv.x); v.y = bf2f(hv.y); v.z = bf2f(hv.z); v.w = bf2f(hv.w);
    float mu, var;
    block_mean_var(v.x + v.y + v.z + v.w,
                   v.x * v.x + v.y * v.y + v.z * v.z + v.w * v.w, red, t, mu, var);
    const float rstd = rsqrtf(var + 1e-5f);
    const float4 wv = reinterpret_cast<const float4*>(w)[t];
    const float4 bv = reinterpret_cast<const float4*>(b)[t];
    const float4 xv = reinterpret_cast<const float4*>(x + (size_t)row * H_DIM)[t];
    float4 o;
    o.x = (v.x - mu) * rstd * wv.x + bv.x + xv.x;
    o.y = (v.y - mu) * rstd * wv.y + bv.y + xv.y;
    o.z = (v.z - mu) * rstd * wv.z + bv.z + xv.z;
    o.w = (v.w - mu) * rstd * wv.w + bv.w + xv.w;
    reinterpret_cast<float4*>(out + (size_t)row * H_DIM)[t] = o;
}

__global__ void cvt_bf16(const float* __restrict__ in, u16* __restrict__ out, int n4) {
    int i = blockIdx.x * blockDim.x + threadIdx.x;
    if (i >= n4) return;
    float4 v = reinterpret_cast<const float4*>(in)[i];
    u16x4 o = { f2bf(v.x), f2bf(v.y), f2bf(v.z), f2bf(v.w) };
    reinterpret_cast<u16x4*>(out)[i] = o;
}

extern "C" void kernel_launch(void* const* d_in, const int* in_sizes, int n_in,
                              void* d_out, int out_size, void* d_ws, size_t ws_size,
                              hipStream_t stream)
{
    const float* x   = (const float*)d_in[0];
    const float* lnw = (const float*)d_in[1];
    const float* lnb = (const float*)d_in[2];
    const float* w1  = (const float*)d_in[3];
    const float* b1  = (const float*)d_in[4];
    const float* w2  = (const float*)d_in[5];
    const float* b2  = (const float*)d_in[6];
    const float* pw  = (const float*)d_in[7];
    const float* pb  = (const float*)d_in[8];
    float* out = (float*)d_out;

    // Workspace layout (peak 96 MiB), liveness-based aliasing:
    //   [0,16M)   xln   (live: ln_pre -> gemm1)
    //   [16,32M)  w1b   (live: cvt -> gemm1)
    //   [32,96M)  hid   (live: gemm1 -> gemm2)
    //   [0,8M)    w2b   (converted AFTER gemm1, over dead xln)
    //   [8,24M)   opb   (bf16, gemm2 out, over dead xln tail + w1b head)
    char* ws = (char*)d_ws;
    u16* xln = (u16*)(ws);
    u16* w1b = (u16*)(ws + (16u << 20));
    u16* hid = (u16*)(ws + (32u << 20));
    u16* w2b = (u16*)(ws);
    u16* opb = (u16*)(ws + (8u << 20));

    cvt_bf16<<<(2 * I_DIM * H_DIM / 4 + 255) / 256, 256, 0, stream>>>(w1, w1b, 2 * I_DIM * H_DIM / 4);
    ln_pre<<<N_ROWS, 256, 0, stream>>>(x, lnw, lnb, xln);
    gemm1_gated<<<dim3(I_DIM / 128, N_ROWS / 256), 512, 0, stream>>>(xln, w1b, b1, hid);
    cvt_bf16<<<(H_DIM * I_DIM / 4 + 255) / 256, 256, 0, stream>>>(w2, w2b, H_DIM * I_DIM / 4);
    gemm2_k<<<dim3(H_DIM / 128, N_ROWS / 256), 512, 0, stream>>>(hid, w2b, b2, opb);
    ln_post_res<<<N_ROWS, 256, 0, stream>>>(opb, pw, pb, x, out);
}

// Round 6
// 270.733 us; speedup vs baseline: 1.0637x; 1.0152x over previous
//
#include <hip/hip_runtime.h>
#include <stdint.h>

#define N_ROWS 8192
#define H_DIM  1024
#define I_DIM  4096

typedef unsigned short u16;
typedef __bf16 bf16x8 __attribute__((ext_vector_type(8)));
typedef float f32x4 __attribute__((ext_vector_type(4)));
typedef u16 u16x4 __attribute__((ext_vector_type(4)));

#define BAR()   asm volatile("s_barrier" ::: "memory")
#define LGKM0() asm volatile("s_waitcnt lgkmcnt(0)" ::: "memory")
#define VMW(n)  asm volatile("s_waitcnt vmcnt(" #n ")" ::: "memory")

__device__ __forceinline__ u16 f2bf(float f) {
    union { float f; uint32_t u; } v; v.f = f;
    uint32_t u = v.u;
    u += 0x7FFFu + ((u >> 16) & 1u);   // RNE
    return (u16)(u >> 16);
}

__device__ __forceinline__ float bf2f(u16 h) {
    union { uint32_t u; float f; } v; v.u = ((uint32_t)h) << 16;
    return v.f;
}

__device__ __forceinline__ float gelu_tanh(float x) {
    float u = 0.7978845608028654f * (x + 0.044715f * x * x * x);
    u = fminf(fmaxf(u, -15.f), 15.f);
    float e = __expf(2.f * u);
    float t = (e - 1.f) / (e + 1.f);
    return 0.5f * x * (1.f + t);
}

// ---- global -> LDS direct (16B per lane) ----
__device__ __forceinline__ void load_lds16(const void* g, void* l) {
    auto gp = reinterpret_cast<const __attribute__((address_space(1))) uint32_t*>(
        reinterpret_cast<uintptr_t>(g));
    auto lp = reinterpret_cast<__attribute__((address_space(3))) uint32_t*>(
        static_cast<uint32_t>(reinterpret_cast<uintptr_t>(l)));
    __builtin_amdgcn_global_load_lds(gp, lp, 16, 0, 0);
}

// =====================================================================
// GEMM1: hid = gelu(xln·W1g^T + bg) * (xln·W1l^T + bl)   (bf16 out)
// m201-style 8-phase schedule. Tile 256 rows x 128 hid-cols (B-panel =
// 256 W-rows: per-wave 32 gate + 32 lin cols interleaved -> in-reg gelu).
// 512 thr / 8 waves (2M x 4N); per-wave 128x64; BK=64 (2 ks-halves).
// LDS: 2 bufs x 64 KiB; regions per buf: A-ks0@0, A-ks1@8192,
//      B-ks0@16384, B-ks1@24576 (u16 offsets), each 256x32.
// 8 phases/iter over K-tiles E=2it (buf0), O=2it+1 (buf1); each phase:
// stage(region going dead) ; ds_read subtile ; BAR ; lgkmcnt(0) ;
// setprio(1) 16 MFMA setprio(0) ; [vmcnt @Ph4/Ph8] ; BAR.
// Every staged region lands 6 phases before its first reader.
// swizzle: k-granule ^ ((row>>1)&3)  (measured 0-conflict r4/r5).
// =====================================================================
__global__ __launch_bounds__(512, 2) void gemm1_gated(
    const u16* __restrict__ A, const u16* __restrict__ W,
    const float* __restrict__ bias, u16* __restrict__ hid)
{
    __shared__ u16 lds[2 * 32768];     // 128 KiB
    const int t = threadIdx.x;
    const int lane = t & 63, wid = t >> 6;
    const int wm = wid >> 2, wn = wid & 3;
    const int g = lane >> 4, r16 = lane & 15;

    const int brow = blockIdx.y * 256;
    const int bcol = blockIdx.x * 128;

    const int tr = t >> 2;
    const int swz8 = ((t & 3) ^ ((tr >> 1) & 3)) * 8;
    const u16* pA = A + (size_t)(brow + tr) * H_DIM + swz8;
    // B LDS row j: wave (j>>6) owns it; f=j&63: f<32 -> gate col, else lin
    const int j0 = tr, j1 = tr + 128;
    const int c0 = bcol + ((j0 >> 6) << 5) + (j0 & 31);
    const int c1 = bcol + ((j1 >> 6) << 5) + (j1 & 31);
    const u16* pB0 = W + (size_t)(((j0 & 63) < 32) ? c0 : (I_DIM + c0)) * H_DIM + swz8;
    const u16* pB1 = W + (size_t)(((j1 & 63) < 32) ? c1 : (I_DIM + c1)) * H_DIM + swz8;
    const int dst = t * 8;

    const int sl  = (g ^ ((r16 >> 1) & 3)) * 8;
    const int rdA = (wm * 128 + r16) * 32 + sl;           // + ks*8192 + m*512
    const int rdB = 16384 + (wn * 64 + r16) * 32 + sl;    // + ks*8192 + n*512

    f32x4 acc[8][4] = {};   // n0,1 = gate; n2,3 = lin

    u16* const B0 = lds;
    u16* const B1 = lds + 32768;

#define STG_A1(S, kk, ks) do { \
    load_lds16(pA + (kk) + (ks) * 32,                       (S) + (ks) * 8192 + dst); \
    load_lds16(pA + (size_t)128 * H_DIM + (kk) + (ks) * 32, (S) + (ks) * 8192 + 4096 + dst); } while (0)
#define STG_B1(S, kk, ks) do { \
    load_lds16(pB0 + (kk) + (ks) * 32, (S) + 16384 + (ks) * 8192 + dst); \
    load_lds16(pB1 + (kk) + (ks) * 32, (S) + 16384 + (ks) * 8192 + 4096 + dst); } while (0)
#define RD_A1(L, ks, mh) { _Pragma("unroll") for (int m = 0; m < 4; ++m) \
    af[m] = *(const bf16x8*)((L) + (ks) * 8192 + rdA + ((mh) * 4 + m) * 512); }
#define RD_B1(L, ks) { _Pragma("unroll") for (int n = 0; n < 4; ++n) \
    bf[n] = *(const bf16x8*)((L) + (ks) * 8192 + rdB + n * 512); }
#define MM1(mh) { _Pragma("unroll") for (int m = 0; m < 4; ++m) _Pragma("unroll") for (int n = 0; n < 4; ++n) \
    acc[(mh) * 4 + m][n] = __builtin_amdgcn_mfma_f32_16x16x32_bf16(af[m], bf[n], acc[(mh) * 4 + m][n], 0, 0, 0); }

    // prologue: buf0 = tile0 complete; buf1 = tile1 ks0 only
    STG_A1(B0, 0, 0); STG_B1(B0, 0, 0);
    STG_A1(B0, 0, 1); STG_B1(B0, 0, 1);
    STG_A1(B1, 64, 0); STG_B1(B1, 64, 0);
    VMW(4); BAR();

    const int NI = H_DIM / 128;   // 8 iterations (2 K-tiles each)
#pragma unroll 1
    for (int it = 0; it < NI; ++it) {
        const int kk1 = (2 * it + 1) * 64;
        const int kk2 = (2 * it + 2) * 64;
        const int kk3 = (2 * it + 3) * 64;
        const bool s2 = (it + 1 < NI);
        const bool last = (it == NI - 1);
        bf16x8 af[4], bf[4];

        // Ph1: stage buf1-ks1(O); compute buf0 ks0 mh0
        STG_A1(B1, kk1, 1); STG_B1(B1, kk1, 1);
        RD_A1(B0, 0, 0); RD_B1(B0, 0);
        BAR(); LGKM0();
        __builtin_amdgcn_s_setprio(1); MM1(0); __builtin_amdgcn_s_setprio(0);
        BAR();

        // Ph2: stage buf0-B-ks0(E+2); compute buf0 ks0 mh1
        if (s2) STG_B1(B0, kk2, 0);
        RD_A1(B0, 0, 1);
        BAR(); LGKM0();
        __builtin_amdgcn_s_setprio(1); MM1(1); __builtin_amdgcn_s_setprio(0);
        BAR();

        // Ph3: stage buf0-A-ks0(E+2); compute buf0 ks1 mh0
        if (s2) STG_A1(B0, kk2, 0);
        RD_A1(B0, 1, 0); RD_B1(B0, 1);
        BAR(); LGKM0();
        __builtin_amdgcn_s_setprio(1); MM1(0); __builtin_amdgcn_s_setprio(0);
        BAR();

        // Ph4: stage buf0-B-ks1(E+2); compute buf0 ks1 mh1; wait
        if (s2) STG_B1(B0, kk2, 1);
        RD_A1(B0, 1, 1);
        BAR(); LGKM0();
        __builtin_amdgcn_s_setprio(1); MM1(1); __builtin_amdgcn_s_setprio(0);
        if (last) { VMW(0); } else { VMW(6); }
        BAR();

        // Ph5: stage buf0-A-ks1(E+2); compute buf1 ks0 mh0
        if (s2) STG_A1(B0, kk2, 1);
        RD_A1(B1, 0, 0); RD_B1(B1, 0);
        BAR(); LGKM0();
        __builtin_amdgcn_s_setprio(1); MM1(0); __builtin_amdgcn_s_setprio(0);
        BAR();

        // Ph6: stage buf1-B-ks0(O+2); compute buf1 ks0 mh1
        if (s2) STG_B1(B1, kk3, 0);
        RD_A1(B1, 0, 1);
        BAR(); LGKM0();
        __builtin_amdgcn_s_setprio(1); MM1(1); __builtin_amdgcn_s_setprio(0);
        BAR();

        // Ph7: stage buf1-A-ks0(O+2); compute buf1 ks1 mh0
        if (s2) STG_A1(B1, kk3, 0);
        RD_A1(B1, 1, 0); RD_B1(B1, 1);
        BAR(); LGKM0();
        __builtin_amdgcn_s_setprio(1); MM1(0); __builtin_amdgcn_s_setprio(0);
        BAR();

        // Ph8: compute buf1 ks1 mh1; wait
        RD_A1(B1, 1, 1);
        BAR(); LGKM0();
        __builtin_amdgcn_s_setprio(1); MM1(1); __builtin_amdgcn_s_setprio(0);
        if (last) { VMW(0); } else { VMW(4); }
        BAR();
    }
#undef STG_A1
#undef STG_B1
#undef RD_A1
#undef RD_B1
#undef MM1

    // epilogue: bias + gated gelu, bf16 store
#pragma unroll
    for (int n = 0; n < 2; ++n) {
        const int cg = bcol + wn * 32 + n * 16 + r16;
        const float bgv = bias[cg], blv = bias[I_DIM + cg];
#pragma unroll
        for (int m = 0; m < 8; ++m) {
            const int row = brow + wm * 128 + m * 16 + g * 4;
            u16* hp = hid + (size_t)row * I_DIM + cg;
#pragma unroll
            for (int r = 0; r < 4; ++r) {
                float gate = acc[m][n][r] + bgv;
                float lin  = acc[m][n + 2][r] + blv;
                hp[(size_t)r * I_DIM] = f2bf(gelu_tanh(gate) * lin);
            }
        }
    }
}

// =====================================================================
// GEMM2: opb = hid·W2^T + b2  (bf16 out) — same 8-phase schedule.
// Tile 256 x 128; 512 thr / 8 waves (4M x 2N); per-wave 64x64; BK=64.
// LDS: 2 bufs x 48 KiB; regions: A-ks0@0, A-ks1@8192 (256x32),
//      B-ks0@16384, B-ks1@20480 (128x32).
// Stage slots mirror gemm1 (A=2 loads, B=1); waits vmcnt(4)@Ph4,
// vmcnt(3)@Ph8; 8 MFMA/phase.
// =====================================================================
__global__ __launch_bounds__(512, 2) void gemm2_k(
    const u16* __restrict__ A, const u16* __restrict__ W,
    const float* __restrict__ bias, u16* __restrict__ opb)
{
    __shared__ u16 lds[2 * 24576];     // 96 KiB
    const int t = threadIdx.x;
    const int lane = t & 63, wid = t >> 6;
    const int wm = wid >> 1, wn = wid & 1;
    const int g = lane >> 4, r16 = lane & 15;

    const int brow = blockIdx.y * 256;
    const int bcol = blockIdx.x * 128;

    const int tr = t >> 2;
    const int swz8 = ((t & 3) ^ ((tr >> 1) & 3)) * 8;
    const u16* pA = A + (size_t)(brow + tr) * I_DIM + swz8;
    const u16* pB = W + (size_t)(bcol + tr) * I_DIM + swz8;
    const int dst = t * 8;

    const int sl  = (g ^ ((r16 >> 1) & 3)) * 8;
    const int rdA = (wm * 64 + r16) * 32 + sl;            // + ks*8192 + m*512
    const int rdB = 16384 + (wn * 64 + r16) * 32 + sl;    // + ks*4096 + n*512

    f32x4 acc[4][4] = {};

    u16* const B0 = lds;
    u16* const B1 = lds + 24576;

#define STG_A2(S, kk, ks) do { \
    load_lds16(pA + (kk) + (ks) * 32,                       (S) + (ks) * 8192 + dst); \
    load_lds16(pA + (size_t)128 * I_DIM + (kk) + (ks) * 32, (S) + (ks) * 8192 + 4096 + dst); } while (0)
#define STG_B2(S, kk, ks) do { \
    load_lds16(pB + (kk) + (ks) * 32, (S) + 16384 + (ks) * 4096 + dst); } while (0)
#define RD_A2(L, ks, mh) { _Pragma("unroll") for (int m = 0; m < 2; ++m) \
    af[m] = *(const bf16x8*)((L) + (ks) * 8192 + rdA + ((mh) * 2 + m) * 512); }
#define RD_B2(L, ks) { _Pragma("unroll") for (int n = 0; n < 4; ++n) \
    bf[n] = *(const bf16x8*)((L) + (ks) * 4096 + rdB + n * 512); }
#define MM2(mh) { _Pragma("unroll") for (int m = 0; m < 2; ++m) _Pragma("unroll") for (int n = 0; n < 4; ++n) \
    acc[(mh) * 2 + m][n] = __builtin_amdgcn_mfma_f32_16x16x32_bf16(af[m], bf[n], acc[(mh) * 2 + m][n], 0, 0, 0); }

    // prologue: buf0 = tile0 complete; buf1 = tile1 ks0 only
    STG_A2(B0, 0, 0); STG_B2(B0, 0, 0);
    STG_A2(B0, 0, 1); STG_B2(B0, 0, 1);
    STG_A2(B1, 64, 0); STG_B2(B1, 64, 0);
    VMW(3); BAR();

    const int NI = I_DIM / 128;   // 32 iterations
#pragma unroll 1
    for (int it = 0; it < NI; ++it) {
        const int kk1 = (2 * it + 1) * 64;
        const int kk2 = (2 * it + 2) * 64;
        const int kk3 = (2 * it + 3) * 64;
        const bool s2 = (it + 1 < NI);
        const bool last = (it == NI - 1);
        bf16x8 af[2], bf[4];

        // Ph1
        STG_A2(B1, kk1, 1); STG_B2(B1, kk1, 1);
        RD_A2(B0, 0, 0); RD_B2(B0, 0);
        BAR(); LGKM0();
        __builtin_amdgcn_s_setprio(1); MM2(0); __builtin_amdgcn_s_setprio(0);
        BAR();

        // Ph2
        if (s2) STG_B2(B0, kk2, 0);
        RD_A2(B0, 0, 1);
        BAR(); LGKM0();
        __builtin_amdgcn_s_setprio(1); MM2(1); __builtin_amdgcn_s_setprio(0);
        BAR();

        // Ph3
        if (s2) STG_A2(B0, kk2, 0);
        RD_A2(B0, 1, 0); RD_B2(B0, 1);
        BAR(); LGKM0();
        __builtin_amdgcn_s_setprio(1); MM2(0); __builtin_amdgcn_s_setprio(0);
        BAR();

        // Ph4 + wait
        if (s2) STG_B2(B0, kk2, 1);
        RD_A2(B0, 1, 1);
        BAR(); LGKM0();
        __builtin_amdgcn_s_setprio(1); MM2(1); __builtin_amdgcn_s_setprio(0);
        if (last) { VMW(0); } else { VMW(4); }
        BAR();

        // Ph5
        if (s2) STG_A2(B0, kk2, 1);
        RD_A2(B1, 0, 0); RD_B2(B1, 0);
        BAR(); LGKM0();
        __builtin_amdgcn_s_setprio(1); MM2(0); __builtin_amdgcn_s_setprio(0);
        BAR();

        // Ph6
        if (s2) STG_B2(B1, kk3, 0);
        RD_A2(B1, 0, 1);
        BAR(); LGKM0();
        __builtin_amdgcn_s_setprio(1); MM2(1); __builtin_amdgcn_s_setprio(0);
        BAR();

        // Ph7
        if (s2) STG_A2(B1, kk3, 0);
        RD_A2(B1, 1, 0); RD_B2(B1, 1);
        BAR(); LGKM0();
        __builtin_amdgcn_s_setprio(1); MM2(0); __builtin_amdgcn_s_setprio(0);
        BAR();

        // Ph8 + wait
        RD_A2(B1, 1, 1);
        BAR(); LGKM0();
        __builtin_amdgcn_s_setprio(1); MM2(1); __builtin_amdgcn_s_setprio(0);
        if (last) { VMW(0); } else { VMW(3); }
        BAR();
    }
#undef STG_A2
#undef STG_B2
#undef RD_A2
#undef RD_B2
#undef MM2

#pragma unroll
    for (int n = 0; n < 4; ++n) {
        const int cg = bcol + wn * 64 + n * 16 + r16;
        const float bv = bias[cg];
#pragma unroll
        for (int m = 0; m < 4; ++m) {
            const int row = brow + wm * 64 + m * 16 + g * 4;
            u16* op = opb + (size_t)row * H_DIM + cg;
#pragma unroll
            for (int r = 0; r < 4; ++r)
                op[(size_t)r * H_DIM] = f2bf(acc[m][n][r] + bv);
        }
    }
}

// ---- block mean/var over one row of 1024 (256 threads x 4 elems) ----
__device__ __forceinline__ void block_mean_var(float s, float s2, float* red, int t,
                                               float& mu, float& var) {
#pragma unroll
    for (int off = 32; off > 0; off >>= 1) {
        s  += __shfl_down(s, off);
        s2 += __shfl_down(s2, off);
    }
    const int wid = t >> 6;
    if ((t & 63) == 0) { red[wid] = s; red[4 + wid] = s2; }
    __syncthreads();
    if (t == 0) {
        float a = red[0] + red[1] + red[2] + red[3];
        float b = red[4] + red[5] + red[6] + red[7];
        red[0] = a * (1.f / H_DIM);
        red[1] = b * (1.f / H_DIM);
    }
    __syncthreads();
    mu = red[0];
    var = red[1] - mu * mu;
}

__global__ void ln_pre(const float* __restrict__ x, const float* __restrict__ w,
                       const float* __restrict__ b, u16* __restrict__ xln)
{
    __shared__ float red[8];
    const int row = blockIdx.x, t = threadIdx.x;
    const float4 v = reinterpret_cast<const float4*>(x + (size_t)row * H_DIM)[t];
    float mu, var;
    block_mean_var(v.x + v.y + v.z + v.w,
                   v.x * v.x + v.y * v.y + v.z * v.z + v.w * v.w, red, t, mu, var);
    const float rstd = rsqrtf(var + 1e-5f);
    const float4 wv = reinterpret_cast<const float4*>(w)[t];
    const float4 bv = reinterpret_cast<const float4*>(b)[t];
    u16x4 o;
    o.x = f2bf((v.x - mu) * rstd * wv.x + bv.x);
    o.y = f2bf((v.y - mu) * rstd * wv.y + bv.y);
    o.z = f2bf((v.z - mu) * rstd * wv.z + bv.z);
    o.w = f2bf((v.w - mu) * rstd * wv.w + bv.w);
    reinterpret_cast<u16x4*>(xln + (size_t)row * H_DIM)[t] = o;
}

__global__ void ln_post_res(const u16* __restrict__ op, const float* __restrict__ w,
                            const float* __restrict__ b, const float* __restrict__ x,
                            float* __restrict__ out)
{
    __shared__ float red[8];
    const int row = blockIdx.x, t = threadIdx.x;
    const u16x4 hv = reinterpret_cast<const u16x4*>(op + (size_t)row * H_DIM)[t];
    float4 v;
    v.x = bf2f(hv.x); v.y = bf2f(hv.y); v.z = bf2f(hv.z); v.w = bf2f(hv.w);
    float mu, var;
    block_mean_var(v.x + v.y + v.z + v.w,
                   v.x * v.x + v.y * v.y + v.z * v.z + v.w * v.w, red, t, mu, var);
    const float rstd = rsqrtf(var + 1e-5f);
    const float4 wv = reinterpret_cast<const float4*>(w)[t];
    const float4 bv = reinterpret_cast<const float4*>(b)[t];
    const float4 xv = reinterpret_cast<const float4*>(x + (size_t)row * H_DIM)[t];
    float4 o;
    o.x = (v.x - mu) * rstd * wv.x + bv.x + xv.x;
    o.y = (v.y - mu) * rstd * wv.y + bv.y + xv.y;
    o.z = (v.z - mu) * rstd * wv.z + bv.z + xv.z;
    o.w = (v.w - mu) * rstd * wv.w + bv.w + xv.w;
    reinterpret_cast<float4*>(out + (size_t)row * H_DIM)[t] = o;
}

__global__ void cvt_bf16(const float* __restrict__ in, u16* __restrict__ out, int n4) {
    int i = blockIdx.x * blockDim.x + threadIdx.x;
    if (i >= n4) return;
    float4 v = reinterpret_cast<const float4*>(in)[i];
    u16x4 o = { f2bf(v.x), f2bf(v.y), f2bf(v.z), f2bf(v.w) };
    reinterpret_cast<u16x4*>(out)[i] = o;
}

extern "C" void kernel_launch(void* const* d_in, const int* in_sizes, int n_in,
                              void* d_out, int out_size, void* d_ws, size_t ws_size,
                              hipStream_t stream)
{
    const float* x   = (const float*)d_in[0];
    const float* lnw = (const float*)d_in[1];
    const float* lnb = (const float*)d_in[2];
    const float* w1  = (const float*)d_in[3];
    const float* b1  = (const float*)d_in[4];
    const float* w2  = (const float*)d_in[5];
    const float* b2  = (const float*)d_in[6];
    const float* pw  = (const float*)d_in[7];
    const float* pb  = (const float*)d_in[8];
    float* out = (float*)d_out;

    // Workspace layout (peak 96 MiB), liveness-based aliasing:
    //   [0,16M)   xln   (live: ln_pre -> gemm1)
    //   [16,32M)  w1b   (live: cvt -> gemm1)
    //   [32,96M)  hid   (live: gemm1 -> gemm2)
    //   [0,8M)    w2b   (converted AFTER gemm1, over dead xln)
    //   [8,24M)   opb   (bf16, gemm2 out, over dead xln tail + w1b head)
    char* ws = (char*)d_ws;
    u16* xln = (u16*)(ws);
    u16* w1b = (u16*)(ws + (16u << 20));
    u16* hid = (u16*)(ws + (32u << 20));
    u16* w2b = (u16*)(ws);
    u16* opb = (u16*)(ws + (8u << 20));

    cvt_bf16<<<(2 * I_DIM * H_DIM / 4 + 255) / 256, 256, 0, stream>>>(w1, w1b, 2 * I_DIM * H_DIM / 4);
    ln_pre<<<N_ROWS, 256, 0, stream>>>(x, lnw, lnb, xln);
    gemm1_gated<<<dim3(I_DIM / 128, N_ROWS / 256), 512, 0, stream>>>(xln, w1b, b1, hid);
    cvt_bf16<<<(H_DIM * I_DIM / 4 + 255) / 256, 256, 0, stream>>>(w2, w2b, H_DIM * I_DIM / 4);
    gemm2_k<<<dim3(H_DIM / 128, N_ROWS / 256), 512, 0, stream>>>(hid, w2b, b2, opb);
    ln_post_res<<<N_ROWS, 256, 0, stream>>>(opb, pw, pb, x, out);
}

// Round 7
// 267.452 us; speedup vs baseline: 1.0767x; 1.0123x over previous
//
#include <hip/hip_runtime.h>
#include <stdint.h>

#define N_ROWS 8192
#define H_DIM  1024
#define I_DIM  4096

typedef unsigned short u16;
typedef __bf16 bf16x8 __attribute__((ext_vector_type(8)));
typedef float f32x4 __attribute__((ext_vector_type(4)));
typedef u16 u16x4 __attribute__((ext_vector_type(4)));

#define BAR()   asm volatile("s_barrier" ::: "memory")
#define LGKM0() asm volatile("s_waitcnt lgkmcnt(0)" ::: "memory")
#define VMW(n)  asm volatile("s_waitcnt vmcnt(" #n ")" ::: "memory")

__device__ __forceinline__ u16 f2bf(float f) {
    union { float f; uint32_t u; } v; v.f = f;
    uint32_t u = v.u;
    u += 0x7FFFu + ((u >> 16) & 1u);   // RNE
    return (u16)(u >> 16);
}

__device__ __forceinline__ float bf2f(u16 h) {
    union { uint32_t u; float f; } v; v.u = ((uint32_t)h) << 16;
    return v.f;
}

__device__ __forceinline__ float gelu_tanh(float x) {
    float u = 0.7978845608028654f * (x + 0.044715f * x * x * x);
    u = fminf(fmaxf(u, -15.f), 15.f);
    float e = __expf(2.f * u);
    float t = (e - 1.f) / (e + 1.f);
    return 0.5f * x * (1.f + t);
}

// ---- global -> LDS direct (16B per lane) ----
__device__ __forceinline__ void load_lds16(const void* g, void* l) {
    auto gp = reinterpret_cast<const __attribute__((address_space(1))) uint32_t*>(
        reinterpret_cast<uintptr_t>(g));
    auto lp = reinterpret_cast<__attribute__((address_space(3))) uint32_t*>(
        static_cast<uint32_t>(reinterpret_cast<uintptr_t>(l)));
    __builtin_amdgcn_global_load_lds(gp, lp, 16, 0, 0);
}

// =====================================================================
// GEMM1 (persistent): hid = gelu(xln·W1g^T+bg)*(xln·W1l^T+bl), bf16 out.
// Grid 256 = 32 row-panels x 8 col-groups; each block sweeps 4 col-tiles
// of 128 hid-cols with ONE warm pipeline (virtual K-tile index n=0..63,
// ct=n>>4, kt=n&15). 8 waves (2M x 4N), per-wave 128 rows x (32 gate +
// 32 lin) cols; BK=64 (2 ks); 2 LDS bufs x 64 KiB (A@0, B@16384/u16).
// 8 phases/iter, 16 MFMA each; waits VMW(6)@Ph4, VMW(4)@Ph8 (r6-proven
// ledger: every staged region lands >=4 phases before first read).
// Epilogue per col-tile at (it&7)==7: bias+gelu+store, acc reset.
// swizzle: k-granule ^ ((row>>1)&3) (measured 0-conflict r4-r6).
// =====================================================================
__global__ __launch_bounds__(512, 2) void gemm1_gated(
    const u16* __restrict__ A, const u16* __restrict__ W,
    const float* __restrict__ bias, u16* __restrict__ hid)
{
    __shared__ u16 lds[2 * 32768];     // 128 KiB
    const int t = threadIdx.x;
    const int lane = t & 63, wid = t >> 6;
    const int wm = wid >> 2, wn = wid & 3;
    const int g = lane >> 4, r16 = lane & 15;

    const int brow  = blockIdx.y * 256;
    const int bcol0 = blockIdx.x * 512;     // 4 col-tiles of 128

    const int tr = t >> 2;
    const int swz8 = ((t & 3) ^ ((tr >> 1) & 3)) * 8;
    const u16* pA = A + (size_t)(brow + tr) * H_DIM + swz8;
    // B LDS row j: wave (j>>6) owns it; f=j&63: f<32 -> gate col, else lin
    const int j0 = tr, j1 = tr + 128;
    const int c0 = bcol0 + ((j0 >> 6) << 5) + (j0 & 31);
    const int c1 = bcol0 + ((j1 >> 6) << 5) + (j1 & 31);
    const u16* pB0 = W + (size_t)(((j0 & 63) < 32) ? c0 : (I_DIM + c0)) * H_DIM + swz8;
    const u16* pB1 = W + (size_t)(((j1 & 63) < 32) ? c1 : (I_DIM + c1)) * H_DIM + swz8;
    const int dst = t * 8;

    const int sl  = (g ^ ((r16 >> 1) & 3)) * 8;
    const int rdA = (wm * 128 + r16) * 32 + sl;           // + ks*8192 + m*512
    const int rdB = 16384 + (wn * 64 + r16) * 32 + sl;    // + ks*8192 + n*512

    f32x4 acc[8][4] = {};   // n0,1 = gate; n2,3 = lin

    u16* const B0 = lds;
    u16* const B1 = lds + 32768;

#define AOFF(n) (((n) & 15) * 64)
#define BOFF(n) ((size_t)((n) >> 4) * (128 * H_DIM) + (size_t)(((n) & 15) * 64))
#define STG_A1(S, ao, ks) do { \
    load_lds16(pA + (ao) + (ks) * 32,                       (S) + (ks) * 8192 + dst); \
    load_lds16(pA + (size_t)128 * H_DIM + (ao) + (ks) * 32, (S) + (ks) * 8192 + 4096 + dst); } while (0)
#define STG_B1(S, bo, ks) do { \
    load_lds16(pB0 + (bo) + (ks) * 32, (S) + 16384 + (ks) * 8192 + dst); \
    load_lds16(pB1 + (bo) + (ks) * 32, (S) + 16384 + (ks) * 8192 + 4096 + dst); } while (0)
#define RD_A1(L, ks, mh) { _Pragma("unroll") for (int m = 0; m < 4; ++m) \
    af[m] = *(const bf16x8*)((L) + (ks) * 8192 + rdA + ((mh) * 4 + m) * 512); }
#define RD_B1(L, ks) { _Pragma("unroll") for (int n = 0; n < 4; ++n) \
    bf[n] = *(const bf16x8*)((L) + (ks) * 8192 + rdB + n * 512); }
#define MM1(mh) { _Pragma("unroll") for (int m = 0; m < 4; ++m) _Pragma("unroll") for (int n = 0; n < 4; ++n) \
    acc[(mh) * 4 + m][n] = __builtin_amdgcn_mfma_f32_16x16x32_bf16(af[m], bf[n], acc[(mh) * 4 + m][n], 0, 0, 0); }

    // prologue: buf0 = tile0 complete; buf1 = tile1 ks0 only
    STG_A1(B0, 0, 0); STG_B1(B0, (size_t)0, 0);
    STG_A1(B0, 0, 1); STG_B1(B0, (size_t)0, 1);
    STG_A1(B1, AOFF(1), 0); STG_B1(B1, BOFF(1), 0);
    VMW(4); BAR();

    const int NI = 32;   // 64 virtual K-tiles, 2 per iter (4 col-tiles x K=1024)
#pragma unroll 1
    for (int it = 0; it < NI; ++it) {
        const int nO = 2 * it + 1, nE2 = 2 * it + 2, nO2 = 2 * it + 3;
        const int    aO = AOFF(nO), aE2 = AOFF(nE2), aO2 = AOFF(nO2);
        const size_t bO = BOFF(nO), bE2 = BOFF(nE2), bO2 = BOFF(nO2);
        const bool s2 = (it + 1 < NI);
        const bool last = (it == NI - 1);
        bf16x8 af[4], bf[4];

        // Ph1: stage buf1-ks1(O); compute buf0 ks0 mh0
        STG_A1(B1, aO, 1); STG_B1(B1, bO, 1);
        RD_A1(B0, 0, 0); RD_B1(B0, 0);
        BAR(); LGKM0();
        __builtin_amdgcn_s_setprio(1); MM1(0); __builtin_amdgcn_s_setprio(0);
        BAR();

        // Ph2: stage buf0-B-ks0(E+2); compute buf0 ks0 mh1
        if (s2) STG_B1(B0, bE2, 0);
        RD_A1(B0, 0, 1);
        BAR(); LGKM0();
        __builtin_amdgcn_s_setprio(1); MM1(1); __builtin_amdgcn_s_setprio(0);
        BAR();

        // Ph3: stage buf0-A-ks0(E+2); compute buf0 ks1 mh0
        if (s2) STG_A1(B0, aE2, 0);
        RD_A1(B0, 1, 0); RD_B1(B0, 1);
        BAR(); LGKM0();
        __builtin_amdgcn_s_setprio(1); MM1(0); __builtin_amdgcn_s_setprio(0);
        BAR();

        // Ph4: stage buf0-B-ks1(E+2); compute buf0 ks1 mh1; wait
        if (s2) STG_B1(B0, bE2, 1);
        RD_A1(B0, 1, 1);
        BAR(); LGKM0();
        __builtin_amdgcn_s_setprio(1); MM1(1); __builtin_amdgcn_s_setprio(0);
        if (last) { VMW(0); } else { VMW(6); }
        BAR();

        // Ph5: stage buf0-A-ks1(E+2); compute buf1 ks0 mh0
        if (s2) STG_A1(B0, aE2, 1);
        RD_A1(B1, 0, 0); RD_B1(B1, 0);
        BAR(); LGKM0();
        __builtin_amdgcn_s_setprio(1); MM1(0); __builtin_amdgcn_s_setprio(0);
        BAR();

        // Ph6: stage buf1-B-ks0(O+2); compute buf1 ks0 mh1
        if (s2) STG_B1(B1, bO2, 0);
        RD_A1(B1, 0, 1);
        BAR(); LGKM0();
        __builtin_amdgcn_s_setprio(1); MM1(1); __builtin_amdgcn_s_setprio(0);
        BAR();

        // Ph7: stage buf1-A-ks0(O+2); compute buf1 ks1 mh0
        if (s2) STG_A1(B1, aO2, 0);
        RD_A1(B1, 1, 0); RD_B1(B1, 1);
        BAR(); LGKM0();
        __builtin_amdgcn_s_setprio(1); MM1(0); __builtin_amdgcn_s_setprio(0);
        BAR();

        // Ph8: compute buf1 ks1 mh1; wait
        RD_A1(B1, 1, 1);
        BAR(); LGKM0();
        __builtin_amdgcn_s_setprio(1); MM1(1); __builtin_amdgcn_s_setprio(0);
        if (last) { VMW(0); } else { VMW(4); }
        BAR();

        // per-col-tile epilogue: bias + gated gelu, bf16 store, acc reset
        if ((it & 7) == 7) {
            const int ct = it >> 3;
#pragma unroll
            for (int n = 0; n < 2; ++n) {
                const int cg = bcol0 + ct * 128 + wn * 32 + n * 16 + r16;
                const float bgv = bias[cg], blv = bias[I_DIM + cg];
#pragma unroll
                for (int m = 0; m < 8; ++m) {
                    const int row = brow + wm * 128 + m * 16 + g * 4;
                    u16* hp = hid + (size_t)row * I_DIM + cg;
#pragma unroll
                    for (int r = 0; r < 4; ++r) {
                        float gate = acc[m][n][r] + bgv;
                        float lin  = acc[m][n + 2][r] + blv;
                        hp[(size_t)r * I_DIM] = f2bf(gelu_tanh(gate) * lin);
                        acc[m][n][r] = 0.f;
                        acc[m][n + 2][r] = 0.f;
                    }
                }
            }
        }
    }
#undef AOFF
#undef BOFF
#undef STG_A1
#undef STG_B1
#undef RD_A1
#undef RD_B1
#undef MM1
}

// =====================================================================
// GEMM2: opb = hid·W2^T + b2 (bf16 out). 4 phases/iter x 16 MFMA.
// Tile 256 x 128; 8 waves (4M x 2N); per-wave 64x64; BK=64 (2 ks).
// LDS: 2 bufs x 48 KiB; regions: A-ks0@0, A-ks1@8192 (256x32),
//      B-ks0@16384, B-ks1@20480 (128x32).
// Phase = one K-32 slice x full acc: 3 stage loads + 8 ds_read + 16 MFMA;
// VMW(6) at every phase end (completes exactly the 3-phase-old group).
// Stage map: Ph1->B1ks1(O), Ph2->B0ks0(E+2), Ph3->B0ks1(E+2),
//            Ph4->B1ks0(O+2). Tail: 6,3,0 on last iter.
// =====================================================================
__global__ __launch_bounds__(512, 2) void gemm2_k(
    const u16* __restrict__ A, const u16* __restrict__ W,
    const float* __restrict__ bias, u16* __restrict__ opb)
{
    __shared__ u16 lds[2 * 24576];     // 96 KiB
    const int t = threadIdx.x;
    const int lane = t & 63, wid = t >> 6;
    const int wm = wid >> 1, wn = wid & 1;
    const int g = lane >> 4, r16 = lane & 15;

    const int brow = blockIdx.y * 256;
    const int bcol = blockIdx.x * 128;

    const int tr = t >> 2;
    const int swz8 = ((t & 3) ^ ((tr >> 1) & 3)) * 8;
    const u16* pA = A + (size_t)(brow + tr) * I_DIM + swz8;
    const u16* pB = W + (size_t)(bcol + tr) * I_DIM + swz8;
    const int dst = t * 8;

    const int sl  = (g ^ ((r16 >> 1) & 3)) * 8;
    const int rdA = (wm * 64 + r16) * 32 + sl;            // + ks*8192 + m*512
    const int rdB = 16384 + (wn * 64 + r16) * 32 + sl;    // + ks*4096 + n*512

    f32x4 acc[4][4] = {};

    u16* const B0 = lds;
    u16* const B1 = lds + 24576;

#define STG_A2(S, kk, ks) do { \
    load_lds16(pA + (kk) + (ks) * 32,                       (S) + (ks) * 8192 + dst); \
    load_lds16(pA + (size_t)128 * I_DIM + (kk) + (ks) * 32, (S) + (ks) * 8192 + 4096 + dst); } while (0)
#define STG_B2(S, kk, ks) do { \
    load_lds16(pB + (kk) + (ks) * 32, (S) + 16384 + (ks) * 4096 + dst); } while (0)
#define RD2(L, ks) { _Pragma("unroll") for (int m = 0; m < 4; ++m) \
    af[m] = *(const bf16x8*)((L) + (ks) * 8192 + rdA + m * 512); \
    _Pragma("unroll") for (int n = 0; n < 4; ++n) \
    bf[n] = *(const bf16x8*)((L) + (ks) * 4096 + rdB + n * 512); }
#define MM2() { _Pragma("unroll") for (int m = 0; m < 4; ++m) _Pragma("unroll") for (int n = 0; n < 4; ++n) \
    acc[m][n] = __builtin_amdgcn_mfma_f32_16x16x32_bf16(af[m], bf[n], acc[m][n], 0, 0, 0); }

    // prologue groups: G1=t0ks0, G2=t0ks1, G3=t1ks0 (3 loads each)
    STG_A2(B0, 0, 0); STG_B2(B0, 0, 0);
    STG_A2(B0, 0, 1); STG_B2(B0, 0, 1);
    STG_A2(B1, 64, 0); STG_B2(B1, 64, 0);
    VMW(6); BAR();   // G1 landed; G2,G3 in flight

    const int NI = I_DIM / 128;   // 32 iterations
#pragma unroll 1
    for (int it = 0; it < NI; ++it) {
        const int kkO  = (2 * it + 1) * 64;
        const int kkE2 = (2 * it + 2) * 64;
        const int kkO2 = (2 * it + 3) * 64;
        const bool s2 = (it + 1 < NI);
        const bool last = (it == NI - 1);
        bf16x8 af[4], bf[4];

        // Ph1: stage B1ks1(O); compute buf0 ks0
        STG_A2(B1, kkO, 1); STG_B2(B1, kkO, 1);
        RD2(B0, 0);
        BAR(); LGKM0();
        __builtin_amdgcn_s_setprio(1); MM2(); __builtin_amdgcn_s_setprio(0);
        VMW(6);
        BAR();

        // Ph2: stage B0ks0(E+2); compute buf0 ks1
        if (s2) { STG_A2(B0, kkE2, 0); STG_B2(B0, kkE2, 0); }
        RD2(B0, 1);
        BAR(); LGKM0();
        __builtin_amdgcn_s_setprio(1); MM2(); __builtin_amdgcn_s_setprio(0);
        if (last) { VMW(3); } else { VMW(6); }
        BAR();

        // Ph3: stage B0ks1(E+2); compute buf1 ks0
        if (s2) { STG_A2(B0, kkE2, 1); STG_B2(B0, kkE2, 1); }
        RD2(B1, 0);
        BAR(); LGKM0();
        __builtin_amdgcn_s_setprio(1); MM2(); __builtin_amdgcn_s_setprio(0);
        if (last) { VMW(0); } else { VMW(6); }
        BAR();

        // Ph4: stage B1ks0(O+2); compute buf1 ks1
        if (s2) { STG_A2(B1, kkO2, 0); STG_B2(B1, kkO2, 0); }
        RD2(B1, 1);
        BAR(); LGKM0();
        __builtin_amdgcn_s_setprio(1); MM2(); __builtin_amdgcn_s_setprio(0);
        if (!last) { VMW(6); }
        BAR();
    }
#undef STG_A2
#undef STG_B2
#undef RD2
#undef MM2

#pragma unroll
    for (int n = 0; n < 4; ++n) {
        const int cg = bcol + wn * 64 + n * 16 + r16;
        const float bv = bias[cg];
#pragma unroll
        for (int m = 0; m < 4; ++m) {
            const int row = brow + wm * 64 + m * 16 + g * 4;
            u16* op = opb + (size_t)row * H_DIM + cg;
#pragma unroll
            for (int r = 0; r < 4; ++r)
                op[(size_t)r * H_DIM] = f2bf(acc[m][n][r] + bv);
        }
    }
}

// ---- block mean/var over one row of 1024 (256 threads x 4 elems) ----
__device__ __forceinline__ void block_mean_var(float s, float s2, float* red, int t,
                                               float& mu, float& var) {
#pragma unroll
    for (int off = 32; off > 0; off >>= 1) {
        s  += __shfl_down(s, off);
        s2 += __shfl_down(s2, off);
    }
    const int wid = t >> 6;
    if ((t & 63) == 0) { red[wid] = s; red[4 + wid] = s2; }
    __syncthreads();
    if (t == 0) {
        float a = red[0] + red[1] + red[2] + red[3];
        float b = red[4] + red[5] + red[6] + red[7];
        red[0] = a * (1.f / H_DIM);
        red[1] = b * (1.f / H_DIM);
    }
    __syncthreads();
    mu = red[0];
    var = red[1] - mu * mu;
}

// ---- fused prep: ln_pre (blocks 0..8191) + w1 cvt (8192..16383) +
//                  w2 cvt (16384..20479) ----
__global__ __launch_bounds__(256) void prep(
    const float* __restrict__ x, const float* __restrict__ lnw,
    const float* __restrict__ lnb, u16* __restrict__ xln,
    const float* __restrict__ w1, u16* __restrict__ w1b,
    const float* __restrict__ w2, u16* __restrict__ w2b)
{
    __shared__ float red[8];
    const int bid = blockIdx.x, t = threadIdx.x;
    if (bid < N_ROWS) {
        const float4 v = reinterpret_cast<const float4*>(x + (size_t)bid * H_DIM)[t];
        float mu, var;
        block_mean_var(v.x + v.y + v.z + v.w,
                       v.x * v.x + v.y * v.y + v.z * v.z + v.w * v.w, red, t, mu, var);
        const float rstd = rsqrtf(var + 1e-5f);
        const float4 wv = reinterpret_cast<const float4*>(lnw)[t];
        const float4 bv = reinterpret_cast<const float4*>(lnb)[t];
        u16x4 o;
        o.x = f2bf((v.x - mu) * rstd * wv.x + bv.x);
        o.y = f2bf((v.y - mu) * rstd * wv.y + bv.y);
        o.z = f2bf((v.z - mu) * rstd * wv.z + bv.z);
        o.w = f2bf((v.w - mu) * rstd * wv.w + bv.w);
        reinterpret_cast<u16x4*>(xln + (size_t)bid * H_DIM)[t] = o;
    } else if (bid < N_ROWS + 8192) {
        const int i = (bid - N_ROWS) * 256 + t;          // 2*I*H/4 = 2097152 exact
        const float4 v = reinterpret_cast<const float4*>(w1)[i];
        u16x4 o = { f2bf(v.x), f2bf(v.y), f2bf(v.z), f2bf(v.w) };
        reinterpret_cast<u16x4*>(w1b)[i] = o;
    } else {
        const int i = (bid - N_ROWS - 8192) * 256 + t;   // H*I/4 = 1048576 exact
        const float4 v = reinterpret_cast<const float4*>(w2)[i];
        u16x4 o = { f2bf(v.x), f2bf(v.y), f2bf(v.z), f2bf(v.w) };
        reinterpret_cast<u16x4*>(w2b)[i] = o;
    }
}

// post-LN over bf16 'op' rows + fp32 residual add
__global__ void ln_post_res(const u16* __restrict__ op, const float* __restrict__ w,
                            const float* __restrict__ b, const float* __restrict__ x,
                            float* __restrict__ out)
{
    __shared__ float red[8];
    const int row = blockIdx.x, t = threadIdx.x;
    const u16x4 hv = reinterpret_cast<const u16x4*>(op + (size_t)row * H_DIM)[t];
    float4 v;
    v.x = bf2f(hv.x); v.y = bf2f(hv.y); v.z = bf2f(hv.z); v.w = bf2f(hv.w);
    float mu, var;
    block_mean_var(v.x + v.y + v.z + v.w,
                   v.x * v.x + v.y * v.y + v.z * v.z + v.w * v.w, red, t, mu, var);
    const float rstd = rsqrtf(var + 1e-5f);
    const float4 wv = reinterpret_cast<const float4*>(w)[t];
    const float4 bv = reinterpret_cast<const float4*>(b)[t];
    const float4 xv = reinterpret_cast<const float4*>(x + (size_t)row * H_DIM)[t];
    float4 o;
    o.x = (v.x - mu) * rstd * wv.x + bv.x + xv.x;
    o.y = (v.y - mu) * rstd * wv.y + bv.y + xv.y;
    o.z = (v.z - mu) * rstd * wv.z + bv.z + xv.z;
    o.w = (v.w - mu) * rstd * wv.w + bv.w + xv.w;
    reinterpret_cast<float4*>(out + (size_t)row * H_DIM)[t] = o;
}

extern "C" void kernel_launch(void* const* d_in, const int* in_sizes, int n_in,
                              void* d_out, int out_size, void* d_ws, size_t ws_size,
                              hipStream_t stream)
{
    const float* x   = (const float*)d_in[0];
    const float* lnw = (const float*)d_in[1];
    const float* lnb = (const float*)d_in[2];
    const float* w1  = (const float*)d_in[3];
    const float* b1  = (const float*)d_in[4];
    const float* w2  = (const float*)d_in[5];
    const float* b2  = (const float*)d_in[6];
    const float* pw  = (const float*)d_in[7];
    const float* pb  = (const float*)d_in[8];
    float* out = (float*)d_out;

    // Workspace layout (peak 96 MiB), liveness-based aliasing:
    //   [0,16M)   xln   (live: prep -> gemm1)
    //   [16,32M)  w1b   (live: prep -> gemm1)
    //   [32,96M)  hid   (live: gemm1 -> gemm2)
    //   [24,32M)  w2b   (live: prep -> gemm2; over w1b tail, dead after gemm1?
    //                    NO - w2b written by prep BEFORE gemm1 reads w1b!
    //                    -> place w2b in its own space below opb instead)
    //   safe layout: xln [0,16M) | w1b [16,32M) | hid [32,96M) |
    //                w2b over xln' is WRONG (prep writes before gemm1)...
    // Final layout (no aliasing conflicts, peak 96 MiB):
    //   xln [0,16M) | w1b [16,32M) | hid [32,96M)
    //   w2b [0,8M)  -- written by prep, but xln also lives there? NO.
    // => w2b gets [8,16M)?? xln needs all 16M. Use hid tail instead:
    //   w2b at [88,96M): hid is 64MB at [32,96); gemm1 writes all of hid ->
    //   would clobber w2b. => extend: keep w2b in dedicated [96,104M)
    //   and opb over dead xln [0,16M) after gemm1. Peak 104 MiB.
    char* ws = (char*)d_ws;
    u16* xln = (u16*)(ws);
    u16* w1b = (u16*)(ws + (16u << 20));
    u16* hid = (u16*)(ws + (32u << 20));
    u16* w2b = (u16*)(ws + (96u << 20));
    u16* opb = (u16*)(ws);   // over dead xln after gemm1

    prep<<<20480, 256, 0, stream>>>(x, lnw, lnb, xln, w1, w1b, w2, w2b);
    gemm1_gated<<<dim3(8, N_ROWS / 256), 512, 0, stream>>>(xln, w1b, b1, hid);
    gemm2_k<<<dim3(H_DIM / 128, N_ROWS / 256), 512, 0, stream>>>(hid, w2b, b2, opb);
    ln_post_res<<<N_ROWS, 256, 0, stream>>>(opb, pw, pb, x, out);
}